// Round 11
// baseline (140.911 us; speedup 1.0000x reference)
//
#include <hip/hip_runtime.h>
#include <math.h>

// Match XLA/LAPACK f32 rounding: no FMA contraction anywhere in this file.
#pragma clang fp contract(off)

#define NPTS 4096
#define NBATCH 4
#define NTOT (NBATCH * NPTS)
#define NNB 20
#define NBINS 5
#define LTOP 7    // per-lane top-list size; P(lane holds >=8 of top-20) ~ 5e-4 total

// f32 LAPACK machine constants
#define SEPS    5.9604644775390625e-8f   // SLAMCH('E') = 2^-24
#define SSAFMIN 1.17549435e-38f          // SLAMCH('S') = 2^-126

// ---------------- LAPACK helpers (f32, faithful to reference LAPACK >= 3.10) ----------------

__device__ __forceinline__ float f_signf(float a, float b) {
  return __builtin_signbit(b) ? -fabsf(a) : fabsf(a);
}

__device__ float slapy2_(float x, float y) {
  float xa = fabsf(x), ya = fabsf(y);
  float w = fmaxf(xa, ya), z = fminf(xa, ya);
  if (z == 0.0f) return w;
  float t = z / w;
  return w * sqrtf(1.0f + t * t);
}

// LAPACK >= 3.10 slartg (c = |f|/d >= 0, r = sign(f)*d); unscaled path (values are moderate)
__device__ void slartg_(float f, float g, float* c, float* s, float* r) {
  if (g == 0.0f) {
    *c = 1.0f; *s = 0.0f; *r = f;
  } else if (f == 0.0f) {
    *c = 0.0f; *s = __builtin_signbit(g) ? -1.0f : 1.0f; *r = fabsf(g);
  } else {
    float f1 = fabsf(f);
    float d = sqrtf(f * f + g * g);
    *c = f1 / d;
    float rr = __builtin_signbit(f) ? -d : d;
    *r = rr;
    *s = g / rr;
  }
}

__device__ void slaev2_(float a, float b, float c,
                        float* rt1, float* rt2, float* cs1, float* sn1) {
  float sm = a + c;
  float df = a - c;
  float adf = fabsf(df);
  float tb = b + b;
  float ab = fabsf(tb);
  float acmx, acmn;
  if (fabsf(a) > fabsf(c)) { acmx = a; acmn = c; } else { acmx = c; acmn = a; }
  float rt;
  if (adf > ab)      { float t = ab / adf; rt = adf * sqrtf(1.0f + t * t); }
  else if (adf < ab) { float t = adf / ab; rt = ab * sqrtf(1.0f + t * t); }
  else               { rt = ab * sqrtf(2.0f); }
  int sgn1;
  if (sm < 0.0f) {
    *rt1 = 0.5f * (sm - rt); sgn1 = -1;
    *rt2 = (acmx / *rt1) * acmn - (b / *rt1) * b;
  } else if (sm > 0.0f) {
    *rt1 = 0.5f * (sm + rt); sgn1 = 1;
    *rt2 = (acmx / *rt1) * acmn - (b / *rt1) * b;
  } else {
    *rt1 = 0.5f * rt; *rt2 = -0.5f * rt; sgn1 = 1;
  }
  float cs; int sgn2;
  if (df >= 0.0f) { cs = df + rt; sgn2 = 1; }
  else            { cs = df - rt; sgn2 = -1; }
  float acs = fabsf(cs);
  float csv, snv;
  if (acs > ab) {
    float ct = -tb / cs;
    snv = 1.0f / sqrtf(1.0f + ct * ct);
    csv = ct * snv;
  } else {
    if (ab == 0.0f) { csv = 1.0f; snv = 0.0f; }
    else {
      float tn = -cs / tb;
      csv = 1.0f / sqrtf(1.0f + tn * tn);
      snv = tn * csv;
    }
  }
  if (sgn1 == sgn2) { float tn = csv; csv = -snv; snv = tn; }
  *cs1 = csv; *sn1 = snv;
}

// SSTEQR('I', n=3) faithful port
__device__ void ssteqr3(float* d, float* e, float Z[3][3]) {
  const int n = 3;
  const float eps = SEPS;
  const float eps2 = SEPS * SEPS;
  const float safmin = SSAFMIN;
  const int nmaxit = 90;
  int jtot = 0;
  int l1 = 1;
  int l = 0, lsv = 0, lend = 0, lendsv = 0, m = 0, mm = 0;
  float p = 0, g = 0, r = 0, c = 0, s = 0, f = 0, bb = 0, rt1 = 0, rt2 = 0;
  float anorm = 0, tst = 0;
  float wc[2], wsn[2];

L10:
  if (l1 > n) goto L160;
  if (l1 > 1) e[l1 - 2] = 0.0f;
  if (l1 <= n - 1) {
    for (m = l1; m <= n - 1; ++m) {
      tst = fabsf(e[m - 1]);
      if (tst == 0.0f) goto L30;
      if (tst <= (sqrtf(fabsf(d[m - 1])) * sqrtf(fabsf(d[m]))) * eps) {
        e[m - 1] = 0.0f;
        goto L30;
      }
    }
  }
  m = n;
L30:
  l = l1; lsv = l; lend = m; lendsv = lend; l1 = m + 1;
  if (lend == l) goto L10;
  anorm = 0.0f;
  for (int i = l; i <= lend; ++i) anorm = fmaxf(anorm, fabsf(d[i - 1]));
  for (int i = l; i <= lend - 1; ++i) anorm = fmaxf(anorm, fabsf(e[i - 1]));
  if (anorm == 0.0f) goto L10;
  if (fabsf(d[lend - 1]) < fabsf(d[l - 1])) { lend = lsv; l = lendsv; }

  if (lend > l) {
L40:
    if (l != lend) {
      for (m = l; m <= lend - 1; ++m) {
        tst = e[m - 1] * e[m - 1];
        if (tst <= (eps2 * fabsf(d[m - 1])) * fabsf(d[m]) + safmin) goto L60;
      }
    }
    m = lend;
L60:
    if (m < lend) e[m - 1] = 0.0f;
    p = d[l - 1];
    if (m == l) goto L80;
    if (m == l + 1) {
      slaev2_(d[l - 1], e[l - 1], d[l], &rt1, &rt2, &c, &s);
      for (int i = 0; i < n; ++i) {
        float tz = Z[i][l];
        Z[i][l]     = c * tz - s * Z[i][l - 1];
        Z[i][l - 1] = s * tz + c * Z[i][l - 1];
      }
      d[l - 1] = rt1; d[l] = rt2; e[l - 1] = 0.0f;
      l += 2;
      if (l <= lend) goto L40;
      goto L140;
    }
    if (jtot == nmaxit) goto L140;
    jtot++;
    g = (d[l] - p) / (2.0f * e[l - 1]);
    r = slapy2_(g, 1.0f);
    g = d[m - 1] - p + e[l - 1] / (g + f_signf(r, g));
    s = 1.0f; c = 1.0f; p = 0.0f;
    for (int i = m - 1; i >= l; --i) {
      f = s * e[i - 1];
      bb = c * e[i - 1];
      slartg_(g, f, &c, &s, &r);
      if (i != m - 1) e[i] = r;
      g = d[i] - p;
      r = (d[i - 1] - g) * s + 2.0f * c * bb;
      p = s * r;
      d[i] = g + p;
      g = c * r - bb;
      wc[i - 1] = c; wsn[i - 1] = -s;
    }
    mm = m - l + 1;
    for (int j = mm - 1; j >= 1; --j) {
      float ct = wc[l + j - 2], st = wsn[l + j - 2];
      for (int i = 0; i < n; ++i) {
        float tz = Z[i][l + j - 1];
        Z[i][l + j - 1] = ct * tz - st * Z[i][l + j - 2];
        Z[i][l + j - 2] = st * tz + ct * Z[i][l + j - 2];
      }
    }
    d[l - 1] -= p;
    e[l - 1] = g;
    goto L40;
L80:
    d[l - 1] = p;
    l++;
    if (l <= lend) goto L40;
    goto L140;
  } else {
L90:
    if (l != lend) {
      for (m = l; m >= lend + 1; --m) {
        tst = e[m - 2] * e[m - 2];
        if (tst <= (eps2 * fabsf(d[m - 1])) * fabsf(d[m - 2]) + safmin) goto L110;
      }
    }
    m = lend;
L110:
    if (m > lend) e[m - 2] = 0.0f;
    p = d[l - 1];
    if (m == l) goto L130;
    if (m == l - 1) {
      slaev2_(d[l - 2], e[l - 2], d[l - 1], &rt1, &rt2, &c, &s);
      for (int i = 0; i < n; ++i) {
        float tz = Z[i][l - 1];
        Z[i][l - 1] = c * tz - s * Z[i][l - 2];
        Z[i][l - 2] = s * tz + c * Z[i][l - 2];
      }
      d[l - 2] = rt1; d[l - 1] = rt2; e[l - 2] = 0.0f;
      l -= 2;
      if (l >= lend) goto L90;
      goto L140;
    }
    if (jtot == nmaxit) goto L140;
    jtot++;
    g = (d[l - 2] - p) / (2.0f * e[l - 2]);
    r = slapy2_(g, 1.0f);
    g = d[m - 1] - p + e[l - 2] / (g + f_signf(r, g));
    s = 1.0f; c = 1.0f; p = 0.0f;
    for (int i = m; i <= l - 1; ++i) {
      f = s * e[i - 1];
      bb = c * e[i - 1];
      slartg_(g, f, &c, &s, &r);
      if (i != m) e[i - 2] = r;
      g = d[i - 1] - p;
      r = (d[i] - g) * s + 2.0f * c * bb;
      p = s * r;
      d[i - 1] = g + p;
      g = c * r - bb;
      wc[i - 1] = c; wsn[i - 1] = s;
    }
    mm = l - m + 1;
    for (int j = 1; j <= mm - 1; ++j) {
      float ct = wc[m + j - 2], st = wsn[m + j - 2];
      for (int i = 0; i < n; ++i) {
        float tz = Z[i][m + j - 1];
        Z[i][m + j - 1] = ct * tz - st * Z[i][m + j - 2];
        Z[i][m + j - 2] = st * tz + ct * Z[i][m + j - 2];
      }
    }
    d[l - 1] -= p;
    e[l - 2] = g;
    goto L90;
L130:
    d[l - 1] = p;
    l--;
    if (l >= lend) goto L90;
    goto L140;
  }
L140:
  if (jtot < nmaxit) goto L10;
  goto L160;
L160:
  for (int ii = 2; ii <= n; ++ii) {
    int i = ii - 1, k = i;
    float pp = d[i - 1];
    for (int j = ii; j <= n; ++j)
      if (d[j - 1] < pp) { k = j; pp = d[j - 1]; }
    if (k != i) {
      d[k - 1] = d[i - 1]; d[i - 1] = pp;
      for (int row = 0; row < n; ++row) {
        float t2 = Z[row][i - 1]; Z[row][i - 1] = Z[row][k - 1]; Z[row][k - 1] = t2;
      }
    }
  }
}

// ssyevd('V','L') for 3x3: ssytd2 -> ssteqr('I') -> sormtr.
__device__ void eigh3f(float A00, float A10, float A20, float A11, float A21, float A22,
                       float V[3][3]) {
  float d[3], e[2];
  float taui, v2, beta;
  float alpha = A10;
  float xnorm = fabsf(A20);
  if (xnorm == 0.0f) {
    taui = 0.0f; beta = alpha; v2 = 0.0f;
  } else {
    beta = -f_signf(slapy2_(alpha, xnorm), alpha);
    taui = (beta - alpha) / beta;
    v2 = A20 * (1.0f / (alpha - beta));
  }
  float a11 = A11, a21 = A21, a22 = A22;
  if (taui != 0.0f) {
    float w0 = taui * (a11 + a21 * v2);
    float w1 = taui * (a21 + a22 * v2);
    float al = -0.5f * taui * (w0 + w1 * v2);
    w0 += al; w1 += al * v2;
    a11 -= 2.0f * w0;
    a21 -= (v2 * w0 + w1);
    a22 -= 2.0f * (v2 * w1);
  }
  d[0] = A00; d[1] = a11; d[2] = a22;
  e[0] = beta; e[1] = a21;

  float Z[3][3] = {{1.0f, 0.0f, 0.0f}, {0.0f, 1.0f, 0.0f}, {0.0f, 0.0f, 1.0f}};
  ssteqr3(d, e, Z);

  for (int k = 0; k < 3; ++k) {
    float t = taui * (Z[1][k] + v2 * Z[2][k]);
    Z[1][k] -= t;
    Z[2][k] -= t * v2;
  }
  for (int i = 0; i < 3; ++i)
    for (int k = 0; k < 3; ++k) V[i][k] = Z[i][k];
}

// wave64 u32 min-reduce via DPP (row_shr 1/2/4/8 + row_bcast15/31); result valid in lane 63.
__device__ __forceinline__ unsigned wave_min_dpp(unsigned v) {
  unsigned t;
  t = (unsigned)__builtin_amdgcn_update_dpp(-1, (int)v, 0x111, 0xf, 0xf, false); v = t < v ? t : v;
  t = (unsigned)__builtin_amdgcn_update_dpp(-1, (int)v, 0x112, 0xf, 0xf, false); v = t < v ? t : v;
  t = (unsigned)__builtin_amdgcn_update_dpp(-1, (int)v, 0x114, 0xf, 0xf, false); v = t < v ? t : v;
  t = (unsigned)__builtin_amdgcn_update_dpp(-1, (int)v, 0x118, 0xf, 0xf, false); v = t < v ? t : v;
  t = (unsigned)__builtin_amdgcn_update_dpp(-1, (int)v, 0x142, 0xa, 0xf, false); v = t < v ? t : v;
  t = (unsigned)__builtin_amdgcn_update_dpp(-1, (int)v, 0x143, 0xc, 0xf, false); v = t < v ? t : v;
  return v;
}

// ---------------- Kernel A: wave-per-point KNN ----------------
// Composite sort key: f64 bit-concat hi=|d2| f32 bits, lo=idx. For positive finite
// doubles, f64 order == lex unsigned (hi,lo) == (key, idx) == reference stable argsort
// of sqrt(|d2|). (hi <= 0x7F7FFFFF -> never NaN/inf; hi=0 denormals order fine, f64
// denorms never flushed on CDNA.) Insert = closed-form min/max network
// L'[t] = min(L[t], max(cur, L[t-1])), skipped wave-uniformly when no lane improves
// (cur >= L[6] -> network provably a no-op for that lane).
// Extraction: two-stage (hi,lo) u32 DPP min; owner unique (idx embedded).

__global__ __launch_bounds__(1024, 8) void knn_kernel(const float* __restrict__ coords,
                                                      float* __restrict__ nbrD,
                                                      int* __restrict__ nbrI,
                                                      float* __restrict__ d16) {
  __shared__ float4 scs[NPTS];     // 64 KB: {x, y, z, sq}
  int tid = threadIdx.x;
  int wid = tid >> 6;
  int lane = tid & 63;
  int P = blockIdx.x * 16 + wid;   // 16 | 4096, no batch crossing
  int b = P >> 12;
  int p = P & (NPTS - 1);
  const float* cb = coords + (size_t)b * NPTS * 3;

  for (int i = tid; i < NPTS; i += 1024) {
    float x = cb[3 * i + 0], y = cb[3 * i + 1], z = cb[3 * i + 2];
    float sq = (x * x + y * y) + z * z;   // exact ref expression order
    scs[i] = make_float4(x, y, z, sq);
  }
  __syncthreads();

  float4 ci = scs[p];
  float xi = ci.x, yi = ci.y, zi = ci.z, sqi = ci.w;

  const double INF = __hiloint2double(0x7FF00000, 0);   // +inf sentinel (> any composite)
  double L[LTOP];
#pragma unroll
  for (int t = 0; t < LTOP; ++t) L[t] = INF;

#pragma unroll 8
  for (int k = 0; k < NPTS / 64; ++k) {
    int j = k * 64 + lane;
    float4 cj = scs[j];                       // one ds_read_b128
    float dot = (xi * cj.x + yi * cj.y) + zi * cj.z;
    float d2 = (sqi - 2.0f * dot) + cj.w;     // exact ref expression order
    unsigned kb = __float_as_uint(d2) & 0x7FFFFFFFu;   // |d2| bits
    double cur = __hiloint2double((int)kb, j);         // bit-concat composite key
    if (__any(cur < L[LTOP - 1])) {           // wave-uniform skip: no lane improves -> no-op
      double m1 = fmax(cur, L[0]);
      double m2 = fmax(cur, L[1]);
      double m3 = fmax(cur, L[2]);
      double m4 = fmax(cur, L[3]);
      double m5 = fmax(cur, L[4]);
      double m6 = fmax(cur, L[5]);
      L[0] = fmin(L[0], cur);
      L[1] = fmin(L[1], m1);
      L[2] = fmin(L[2], m2);
      L[3] = fmin(L[3], m3);
      L[4] = fmin(L[4], m4);
      L[5] = fmin(L[5], m5);
      L[6] = fmin(L[6], m6);
    }
  }

  unsigned resHi = 0, resLo = 0;
  for (int r = 0; r < NNB; ++r) {
    unsigned hi0 = (unsigned)__double2hiint(L[0]);
    unsigned lo0 = (unsigned)__double2loint(L[0]);
    unsigned gh = wave_min_dpp(hi0);
    gh = (unsigned)__builtin_amdgcn_readlane((int)gh, 63);
    unsigned lom = (hi0 == gh) ? lo0 : 0xFFFFFFFFu;
    unsigned gl = wave_min_dpp(lom);
    gl = (unsigned)__builtin_amdgcn_readlane((int)gl, 63);
    bool mine = (hi0 == gh) && (lo0 == gl);   // idx embedded -> unique owner
#pragma unroll
    for (int t = 0; t < LTOP - 1; ++t) L[t] = mine ? L[t + 1] : L[t];
    L[LTOP - 1] = mine ? INF : L[LTOP - 1];
    if (lane == r) { resHi = gh; resLo = gl; }
  }

  if (lane < NNB) {
    float dist = sqrtf(__uint_as_float(resHi));   // hi word IS the f32 |d2| key bits
    nbrD[(size_t)lane * NTOT + P] = dist;         // transposed [NNB][NTOT]
    nbrI[(size_t)lane * NTOT + P] = (int)resLo;   // lo word IS the index
    if (lane == 16) d16[P] = dist;                // dsort[:,16]
  }
}

// ---------------- Kernel B: per-batch radius = mean(d16) ----------------
// Bit-identical sequential f32 sum; coalesced LDS stage then all 64 lanes redundantly
// run the same dependent add chain on LDS broadcast reads.

__global__ __launch_bounds__(64) void radius_kernel(const float* __restrict__ d16,
                                                    float* __restrict__ radius) {
  __shared__ float buf[NPTS];   // 16 KB
  int b = blockIdx.x;
  int lane = threadIdx.x;
  for (int i = lane; i < NPTS; i += 64) buf[i] = d16[(size_t)b * NPTS + i];
  __syncthreads();
  float s = 0.0f;
  for (int k = 0; k < NPTS; ++k) s += buf[k];   // same-addr LDS reads broadcast; same order
  if (lane == 0) radius[b] = s / 4096.0f;
}

// ---------------- Kernel C: per-point SHOT LRF + log-map + histogram (all f32) ----------------

__global__ __launch_bounds__(64) void shot_kernel(const float* __restrict__ coords,
                                                  const float* __restrict__ radius_arr,
                                                  const float* __restrict__ nbrD,
                                                  const int* __restrict__ nbrI,
                                                  float* __restrict__ out) {
  int g = blockIdx.x * 64 + threadIdx.x;
  if (g >= NTOT) return;
  int b = g >> 12;
  int p = g & (NPTS - 1);
  float radius = radius_arr[b];
  const float* cb = coords + (size_t)b * NPTS * 3;
  float xi = cb[p * 3 + 0], yi = cb[p * 3 + 1], zi = cb[p * 3 + 2];
  float fill = 2.0f * radius / sqrtf(3.0f);

  // coalesced transposed reads of neighbor ids/dists
  int jj[NNB];
  float dd[NNB];
#pragma unroll
  for (int k = 0; k < NNB; ++k) {
    jj[k] = nbrI[(size_t)k * NTOT + g];
    dd[k] = nbrD[(size_t)k * NTOT + g];
  }

  float nbx[NNB], nby[NNB], nbz[NNB], dk[NNB];
#pragma unroll
  for (int k = 0; k < NNB; ++k) {
    int j = jj[k];
    float nx, ny, nz;
    if (dd[k] > radius) { nx = fill; ny = fill; nz = fill; }
    else {
      nx = cb[j * 3 + 0] - xi;
      ny = cb[j * 3 + 1] - yi;
      nz = cb[j * 3 + 2] - zi;
    }
    nbx[k] = nx; nby[k] = ny; nbz[k] = nz;
    dk[k] = sqrtf((nx * nx + ny * ny) + nz * nz);
  }

  float wsum = 0.0f;
  float c00 = 0, c11 = 0, c22 = 0;
  float c01 = 0, c10 = 0, c02 = 0, c20 = 0, c12 = 0, c21 = 0;
  for (int k = 0; k < NNB; ++k) {
    float w = fmaxf(radius - dk[k], 0.0f);
    wsum += w;
    float wx = w * nbx[k], wy = w * nby[k], wz = w * nbz[k];
    c00 += wx * nbx[k]; c01 += wx * nby[k]; c02 += wx * nbz[k];
    c10 += wy * nbx[k]; c11 += wy * nby[k]; c12 += wy * nbz[k];
    c20 += wz * nbx[k]; c21 += wz * nby[k]; c22 += wz * nbz[k];
  }
  float den = wsum + 1e-12f;
  float a00 = c00 / den, a11 = c11 / den, a22 = c22 / den;
  float a01 = c01 / den, a10 = c10 / den;
  float a02 = c02 / den, a20 = c20 / den;
  float a12 = c12 / den, a21 = c21 / den;
  float A10 = 0.5f * (a01 + a10);
  float A20 = 0.5f * (a02 + a20);
  float A21 = 0.5f * (a12 + a21);

  float V[3][3];
  eigh3f(a00, A10, A20, a11, A21, a22, V);

  float xax0 = V[0][2], xax1 = V[1][2], xax2 = V[2][2];
  float zax0 = V[0][0], zax1 = V[1][0], zax2 = V[2][0];

  {
    int pos = 0, neg = 0;
    for (int k = 0; k < NNB; ++k) {
      float dt = (nbx[k] * xax0 + nby[k] * xax1) + nbz[k] * xax2;
      if (dt >= 0.0f) pos++; else neg++;
    }
    if (pos < neg) { xax0 = -xax0; xax1 = -xax1; xax2 = -xax2; }
  }
  {
    int pos = 0, neg = 0;
    for (int k = 0; k < NNB; ++k) {
      float dt = (nbx[k] * zax0 + nby[k] * zax1) + nbz[k] * zax2;
      if (dt >= 0.0f) pos++; else neg++;
    }
    if (pos < neg) { zax0 = -zax0; zax1 = -zax1; zax2 = -zax2; }
  }
  float yax0 = zax1 * xax2 - zax2 * xax1;
  float yax1 = zax2 * xax0 - zax0 * xax2;
  float yax2 = zax0 * xax1 - zax1 * xax0;

  float hist[NBINS * NBINS];
  for (int k = 0; k < NBINS * NBINS; ++k) hist[k] = 0.0f;
  float stp = 2.0f * radius / (float)NBINS;
  for (int k = 0; k < NNB; ++k) {
    float u = (nbx[k] * xax0 + nby[k] * xax1) + nbz[k] * xax2;
    float v = (nbx[k] * yax0 + nby[k] * yax1) + nbz[k] * yax2;
    float pn = sqrtf(u * u + v * v);
    float sc = dk[k] / (pn + 1e-12f);
    float pu = u * sc, pv = v * sc;
    float bxf = floorf((pu + radius) / stp);
    float byf = floorf((pv + radius) / stp);
    if (bxf >= 0.0f && bxf < (float)NBINS && byf >= 0.0f && byf < (float)NBINS) {
      int bx = (int)bxf, by = (int)byf;
      hist[by * NBINS + bx] += 1.0f;
    }
  }
  float cvals[NBINS];
  for (int i = 0; i < NBINS; ++i) cvals[i] = ((float)i * stp - radius) + 0.5f * stp;
  float nrm2 = 0.0f;
  for (int i = 0; i < NBINS; ++i) {
    for (int j = 0; j < NBINS; ++j) {
      float wgt = radius - sqrtf(cvals[i] * cvals[i] + cvals[j] * cvals[j]);
      float h = hist[i * NBINS + j] * wgt;
      hist[i * NBINS + j] = h;
      nrm2 += h * h;
    }
  }
  float nrm = sqrtf(nrm2);
  for (int k = 0; k < NBINS * NBINS; ++k) {
    out[(size_t)g * (NBINS * NBINS) + k] = hist[k] / nrm;
  }
}

// ---------------- Launch ----------------

extern "C" void kernel_launch(void* const* d_in, const int* in_sizes, int n_in,
                              void* d_out, int out_size, void* d_ws, size_t ws_size,
                              hipStream_t stream) {
  const float* coords = (const float*)d_in[0];
  float* out = (float*)d_out;

  float* wsf = (float*)d_ws;
  float* radius = wsf;                            // 4 floats (+pad to 8)
  float* d16 = wsf + 8;                           // 16384 floats
  float* nbrD = wsf + 8 + (size_t)NTOT;           // [NNB][NTOT] floats
  int* nbrI = (int*)(nbrD + (size_t)NNB * NTOT);  // [NNB][NTOT] ints

  knn_kernel<<<NTOT / 16, 1024, 0, stream>>>(coords, nbrD, nbrI, d16);
  radius_kernel<<<NBATCH, 64, 0, stream>>>(d16, radius);
  shot_kernel<<<NTOT / 64, 64, 0, stream>>>(coords, radius, nbrD, nbrI, out);
}

// Round 12
// 129.461 us; speedup vs baseline: 1.0884x; 1.0884x over previous
//
#include <hip/hip_runtime.h>
#include <math.h>

// Match XLA/LAPACK f32 rounding: no FMA contraction anywhere in this file.
#pragma clang fp contract(off)

#define NPTS 4096
#define NBATCH 4
#define NTOT (NBATCH * NPTS)
#define NNB 20
#define NBINS 5
#define LTOP 7    // per-lane top-list size; P(lane holds >=8 of top-20) ~ 5e-4 total

// f32 LAPACK machine constants
#define SEPS    5.9604644775390625e-8f   // SLAMCH('E') = 2^-24
#define SSAFMIN 1.17549435e-38f          // SLAMCH('S') = 2^-126

// ---------------- LAPACK helpers (f32, faithful to reference LAPACK >= 3.10) ----------------

__device__ __forceinline__ float f_signf(float a, float b) {
  return __builtin_signbit(b) ? -fabsf(a) : fabsf(a);
}

__device__ float slapy2_(float x, float y) {
  float xa = fabsf(x), ya = fabsf(y);
  float w = fmaxf(xa, ya), z = fminf(xa, ya);
  if (z == 0.0f) return w;
  float t = z / w;
  return w * sqrtf(1.0f + t * t);
}

// LAPACK >= 3.10 slartg (c = |f|/d >= 0, r = sign(f)*d); unscaled path (values are moderate)
__device__ void slartg_(float f, float g, float* c, float* s, float* r) {
  if (g == 0.0f) {
    *c = 1.0f; *s = 0.0f; *r = f;
  } else if (f == 0.0f) {
    *c = 0.0f; *s = __builtin_signbit(g) ? -1.0f : 1.0f; *r = fabsf(g);
  } else {
    float f1 = fabsf(f);
    float d = sqrtf(f * f + g * g);
    *c = f1 / d;
    float rr = __builtin_signbit(f) ? -d : d;
    *r = rr;
    *s = g / rr;
  }
}

__device__ void slaev2_(float a, float b, float c,
                        float* rt1, float* rt2, float* cs1, float* sn1) {
  float sm = a + c;
  float df = a - c;
  float adf = fabsf(df);
  float tb = b + b;
  float ab = fabsf(tb);
  float acmx, acmn;
  if (fabsf(a) > fabsf(c)) { acmx = a; acmn = c; } else { acmx = c; acmn = a; }
  float rt;
  if (adf > ab)      { float t = ab / adf; rt = adf * sqrtf(1.0f + t * t); }
  else if (adf < ab) { float t = adf / ab; rt = ab * sqrtf(1.0f + t * t); }
  else               { rt = ab * sqrtf(2.0f); }
  int sgn1;
  if (sm < 0.0f) {
    *rt1 = 0.5f * (sm - rt); sgn1 = -1;
    *rt2 = (acmx / *rt1) * acmn - (b / *rt1) * b;
  } else if (sm > 0.0f) {
    *rt1 = 0.5f * (sm + rt); sgn1 = 1;
    *rt2 = (acmx / *rt1) * acmn - (b / *rt1) * b;
  } else {
    *rt1 = 0.5f * rt; *rt2 = -0.5f * rt; sgn1 = 1;
  }
  float cs; int sgn2;
  if (df >= 0.0f) { cs = df + rt; sgn2 = 1; }
  else            { cs = df - rt; sgn2 = -1; }
  float acs = fabsf(cs);
  float csv, snv;
  if (acs > ab) {
    float ct = -tb / cs;
    snv = 1.0f / sqrtf(1.0f + ct * ct);
    csv = ct * snv;
  } else {
    if (ab == 0.0f) { csv = 1.0f; snv = 0.0f; }
    else {
      float tn = -cs / tb;
      csv = 1.0f / sqrtf(1.0f + tn * tn);
      snv = tn * csv;
    }
  }
  if (sgn1 == sgn2) { float tn = csv; csv = -snv; snv = tn; }
  *cs1 = csv; *sn1 = snv;
}

// SSTEQR('I', n=3) faithful port
__device__ void ssteqr3(float* d, float* e, float Z[3][3]) {
  const int n = 3;
  const float eps = SEPS;
  const float eps2 = SEPS * SEPS;
  const float safmin = SSAFMIN;
  const int nmaxit = 90;
  int jtot = 0;
  int l1 = 1;
  int l = 0, lsv = 0, lend = 0, lendsv = 0, m = 0, mm = 0;
  float p = 0, g = 0, r = 0, c = 0, s = 0, f = 0, bb = 0, rt1 = 0, rt2 = 0;
  float anorm = 0, tst = 0;
  float wc[2], wsn[2];

L10:
  if (l1 > n) goto L160;
  if (l1 > 1) e[l1 - 2] = 0.0f;
  if (l1 <= n - 1) {
    for (m = l1; m <= n - 1; ++m) {
      tst = fabsf(e[m - 1]);
      if (tst == 0.0f) goto L30;
      if (tst <= (sqrtf(fabsf(d[m - 1])) * sqrtf(fabsf(d[m]))) * eps) {
        e[m - 1] = 0.0f;
        goto L30;
      }
    }
  }
  m = n;
L30:
  l = l1; lsv = l; lend = m; lendsv = lend; l1 = m + 1;
  if (lend == l) goto L10;
  anorm = 0.0f;
  for (int i = l; i <= lend; ++i) anorm = fmaxf(anorm, fabsf(d[i - 1]));
  for (int i = l; i <= lend - 1; ++i) anorm = fmaxf(anorm, fabsf(e[i - 1]));
  if (anorm == 0.0f) goto L10;
  if (fabsf(d[lend - 1]) < fabsf(d[l - 1])) { lend = lsv; l = lendsv; }

  if (lend > l) {
L40:
    if (l != lend) {
      for (m = l; m <= lend - 1; ++m) {
        tst = e[m - 1] * e[m - 1];
        if (tst <= (eps2 * fabsf(d[m - 1])) * fabsf(d[m]) + safmin) goto L60;
      }
    }
    m = lend;
L60:
    if (m < lend) e[m - 1] = 0.0f;
    p = d[l - 1];
    if (m == l) goto L80;
    if (m == l + 1) {
      slaev2_(d[l - 1], e[l - 1], d[l], &rt1, &rt2, &c, &s);
      for (int i = 0; i < n; ++i) {
        float tz = Z[i][l];
        Z[i][l]     = c * tz - s * Z[i][l - 1];
        Z[i][l - 1] = s * tz + c * Z[i][l - 1];
      }
      d[l - 1] = rt1; d[l] = rt2; e[l - 1] = 0.0f;
      l += 2;
      if (l <= lend) goto L40;
      goto L140;
    }
    if (jtot == nmaxit) goto L140;
    jtot++;
    g = (d[l] - p) / (2.0f * e[l - 1]);
    r = slapy2_(g, 1.0f);
    g = d[m - 1] - p + e[l - 1] / (g + f_signf(r, g));
    s = 1.0f; c = 1.0f; p = 0.0f;
    for (int i = m - 1; i >= l; --i) {
      f = s * e[i - 1];
      bb = c * e[i - 1];
      slartg_(g, f, &c, &s, &r);
      if (i != m - 1) e[i] = r;
      g = d[i] - p;
      r = (d[i - 1] - g) * s + 2.0f * c * bb;
      p = s * r;
      d[i] = g + p;
      g = c * r - bb;
      wc[i - 1] = c; wsn[i - 1] = -s;
    }
    mm = m - l + 1;
    for (int j = mm - 1; j >= 1; --j) {
      float ct = wc[l + j - 2], st = wsn[l + j - 2];
      for (int i = 0; i < n; ++i) {
        float tz = Z[i][l + j - 1];
        Z[i][l + j - 1] = ct * tz - st * Z[i][l + j - 2];
        Z[i][l + j - 2] = st * tz + ct * Z[i][l + j - 2];
      }
    }
    d[l - 1] -= p;
    e[l - 1] = g;
    goto L40;
L80:
    d[l - 1] = p;
    l++;
    if (l <= lend) goto L40;
    goto L140;
  } else {
L90:
    if (l != lend) {
      for (m = l; m >= lend + 1; --m) {
        tst = e[m - 2] * e[m - 2];
        if (tst <= (eps2 * fabsf(d[m - 1])) * fabsf(d[m - 2]) + safmin) goto L110;
      }
    }
    m = lend;
L110:
    if (m > lend) e[m - 2] = 0.0f;
    p = d[l - 1];
    if (m == l) goto L130;
    if (m == l - 1) {
      slaev2_(d[l - 2], e[l - 2], d[l - 1], &rt1, &rt2, &c, &s);
      for (int i = 0; i < n; ++i) {
        float tz = Z[i][l - 1];
        Z[i][l - 1] = c * tz - s * Z[i][l - 2];
        Z[i][l - 2] = s * tz + c * Z[i][l - 2];
      }
      d[l - 2] = rt1; d[l - 1] = rt2; e[l - 2] = 0.0f;
      l -= 2;
      if (l >= lend) goto L90;
      goto L140;
    }
    if (jtot == nmaxit) goto L140;
    jtot++;
    g = (d[l - 2] - p) / (2.0f * e[l - 2]);
    r = slapy2_(g, 1.0f);
    g = d[m - 1] - p + e[l - 2] / (g + f_signf(r, g));
    s = 1.0f; c = 1.0f; p = 0.0f;
    for (int i = m; i <= l - 1; ++i) {
      f = s * e[i - 1];
      bb = c * e[i - 1];
      slartg_(g, f, &c, &s, &r);
      if (i != m) e[i - 2] = r;
      g = d[i - 1] - p;
      r = (d[i] - g) * s + 2.0f * c * bb;
      p = s * r;
      d[i - 1] = g + p;
      g = c * r - bb;
      wc[i - 1] = c; wsn[i - 1] = s;
    }
    mm = l - m + 1;
    for (int j = 1; j <= mm - 1; ++j) {
      float ct = wc[m + j - 2], st = wsn[m + j - 2];
      for (int i = 0; i < n; ++i) {
        float tz = Z[i][m + j - 1];
        Z[i][m + j - 1] = ct * tz - st * Z[i][m + j - 2];
        Z[i][m + j - 2] = st * tz + ct * Z[i][m + j - 2];
      }
    }
    d[l - 1] -= p;
    e[l - 2] = g;
    goto L90;
L130:
    d[l - 1] = p;
    l--;
    if (l >= lend) goto L90;
    goto L140;
  }
L140:
  if (jtot < nmaxit) goto L10;
  goto L160;
L160:
  for (int ii = 2; ii <= n; ++ii) {
    int i = ii - 1, k = i;
    float pp = d[i - 1];
    for (int j = ii; j <= n; ++j)
      if (d[j - 1] < pp) { k = j; pp = d[j - 1]; }
    if (k != i) {
      d[k - 1] = d[i - 1]; d[i - 1] = pp;
      for (int row = 0; row < n; ++row) {
        float t2 = Z[row][i - 1]; Z[row][i - 1] = Z[row][k - 1]; Z[row][k - 1] = t2;
      }
    }
  }
}

// ssyevd('V','L') for 3x3: ssytd2 -> ssteqr('I') -> sormtr.
__device__ void eigh3f(float A00, float A10, float A20, float A11, float A21, float A22,
                       float V[3][3]) {
  float d[3], e[2];
  float taui, v2, beta;
  float alpha = A10;
  float xnorm = fabsf(A20);
  if (xnorm == 0.0f) {
    taui = 0.0f; beta = alpha; v2 = 0.0f;
  } else {
    beta = -f_signf(slapy2_(alpha, xnorm), alpha);
    taui = (beta - alpha) / beta;
    v2 = A20 * (1.0f / (alpha - beta));
  }
  float a11 = A11, a21 = A21, a22 = A22;
  if (taui != 0.0f) {
    float w0 = taui * (a11 + a21 * v2);
    float w1 = taui * (a21 + a22 * v2);
    float al = -0.5f * taui * (w0 + w1 * v2);
    w0 += al; w1 += al * v2;
    a11 -= 2.0f * w0;
    a21 -= (v2 * w0 + w1);
    a22 -= 2.0f * (v2 * w1);
  }
  d[0] = A00; d[1] = a11; d[2] = a22;
  e[0] = beta; e[1] = a21;

  float Z[3][3] = {{1.0f, 0.0f, 0.0f}, {0.0f, 1.0f, 0.0f}, {0.0f, 0.0f, 1.0f}};
  ssteqr3(d, e, Z);

  for (int k = 0; k < 3; ++k) {
    float t = taui * (Z[1][k] + v2 * Z[2][k]);
    Z[1][k] -= t;
    Z[2][k] -= t * v2;
  }
  for (int i = 0; i < 3; ++i)
    for (int k = 0; k < 3; ++k) V[i][k] = Z[i][k];
}

// wave64 u32 min-reduce via DPP (row_shr 1/2/4/8 + row_bcast15/31); result valid in lane 63.
__device__ __forceinline__ unsigned wave_min_dpp(unsigned v) {
  unsigned t;
  t = (unsigned)__builtin_amdgcn_update_dpp(-1, (int)v, 0x111, 0xf, 0xf, false); v = t < v ? t : v;
  t = (unsigned)__builtin_amdgcn_update_dpp(-1, (int)v, 0x112, 0xf, 0xf, false); v = t < v ? t : v;
  t = (unsigned)__builtin_amdgcn_update_dpp(-1, (int)v, 0x114, 0xf, 0xf, false); v = t < v ? t : v;
  t = (unsigned)__builtin_amdgcn_update_dpp(-1, (int)v, 0x118, 0xf, 0xf, false); v = t < v ? t : v;
  t = (unsigned)__builtin_amdgcn_update_dpp(-1, (int)v, 0x142, 0xa, 0xf, false); v = t < v ? t : v;
  t = (unsigned)__builtin_amdgcn_update_dpp(-1, (int)v, 0x143, 0xc, 0xf, false); v = t < v ? t : v;
  return v;
}

// ---------------- Kernel A: wave-per-point KNN ----------------
// Composite sort key: f64 bit-concat hi=|d2| f32 bits, lo=idx. For positive finite
// doubles, f64 order == lex unsigned (hi,lo) == (key, idx) == reference stable argsort
// of sqrt(|d2|). Insert = straight-line closed-form min/max network (R11's wave-uniform
// skip branch REVERTED: it broke the unroll-8 load pipeline and cost +14 us).
// Extraction: two-stage (hi,lo) u32 DPP min; owner unique (idx embedded).

__global__ __launch_bounds__(1024, 8) void knn_kernel(const float* __restrict__ coords,
                                                      float* __restrict__ nbrD,
                                                      int* __restrict__ nbrI,
                                                      float* __restrict__ d16) {
  __shared__ float4 scs[NPTS];     // 64 KB: {x, y, z, sq}
  int tid = threadIdx.x;
  int wid = tid >> 6;
  int lane = tid & 63;
  int P = blockIdx.x * 16 + wid;   // 16 | 4096, no batch crossing
  int b = P >> 12;
  int p = P & (NPTS - 1);
  const float* cb = coords + (size_t)b * NPTS * 3;

  for (int i = tid; i < NPTS; i += 1024) {
    float x = cb[3 * i + 0], y = cb[3 * i + 1], z = cb[3 * i + 2];
    float sq = (x * x + y * y) + z * z;   // exact ref expression order
    scs[i] = make_float4(x, y, z, sq);
  }
  __syncthreads();

  float4 ci = scs[p];
  float xi = ci.x, yi = ci.y, zi = ci.z, sqi = ci.w;

  const double INF = __hiloint2double(0x7FF00000, 0);   // +inf sentinel (> any composite)
  double L[LTOP];
#pragma unroll
  for (int t = 0; t < LTOP; ++t) L[t] = INF;

#pragma unroll 8
  for (int k = 0; k < NPTS / 64; ++k) {
    int j = k * 64 + lane;
    float4 cj = scs[j];                       // one ds_read_b128
    float dot = (xi * cj.x + yi * cj.y) + zi * cj.z;
    float d2 = (sqi - 2.0f * dot) + cj.w;     // exact ref expression order
    unsigned kb = __float_as_uint(d2) & 0x7FFFFFFFu;   // |d2| bits
    double cur = __hiloint2double((int)kb, j);         // bit-concat composite key
    // sorted-insert min/max network (maxes from OLD L values)
    double m1 = fmax(cur, L[0]);
    double m2 = fmax(cur, L[1]);
    double m3 = fmax(cur, L[2]);
    double m4 = fmax(cur, L[3]);
    double m5 = fmax(cur, L[4]);
    double m6 = fmax(cur, L[5]);
    L[0] = fmin(L[0], cur);
    L[1] = fmin(L[1], m1);
    L[2] = fmin(L[2], m2);
    L[3] = fmin(L[3], m3);
    L[4] = fmin(L[4], m4);
    L[5] = fmin(L[5], m5);
    L[6] = fmin(L[6], m6);
  }

  unsigned resHi = 0, resLo = 0;
  for (int r = 0; r < NNB; ++r) {
    unsigned hi0 = (unsigned)__double2hiint(L[0]);
    unsigned lo0 = (unsigned)__double2loint(L[0]);
    unsigned gh = wave_min_dpp(hi0);
    gh = (unsigned)__builtin_amdgcn_readlane((int)gh, 63);
    unsigned lom = (hi0 == gh) ? lo0 : 0xFFFFFFFFu;
    unsigned gl = wave_min_dpp(lom);
    gl = (unsigned)__builtin_amdgcn_readlane((int)gl, 63);
    bool mine = (hi0 == gh) && (lo0 == gl);   // idx embedded -> unique owner
#pragma unroll
    for (int t = 0; t < LTOP - 1; ++t) L[t] = mine ? L[t + 1] : L[t];
    L[LTOP - 1] = mine ? INF : L[LTOP - 1];
    if (lane == r) { resHi = gh; resLo = gl; }
  }

  if (lane < NNB) {
    float dist = sqrtf(__uint_as_float(resHi));   // hi word IS the f32 |d2| key bits
    nbrD[(size_t)lane * NTOT + P] = dist;         // transposed [NNB][NTOT]
    nbrI[(size_t)lane * NTOT + P] = (int)resLo;   // lo word IS the index
    if (lane == 16) d16[P] = dist;                // dsort[:,16]
  }
}

// ---------------- Kernel B: per-batch radius = mean(d16) ----------------
// Bit-identical sequential f32 sum; coalesced LDS stage then all 64 lanes redundantly
// run the same dependent add chain on LDS broadcast reads.

__global__ __launch_bounds__(64) void radius_kernel(const float* __restrict__ d16,
                                                    float* __restrict__ radius) {
  __shared__ float buf[NPTS];   // 16 KB
  int b = blockIdx.x;
  int lane = threadIdx.x;
  for (int i = lane; i < NPTS; i += 64) buf[i] = d16[(size_t)b * NPTS + i];
  __syncthreads();
  float s = 0.0f;
  for (int k = 0; k < NPTS; ++k) s += buf[k];   // same-addr LDS reads broadcast; same order
  if (lane == 0) radius[b] = s / 4096.0f;
}

// ---------------- Kernel C: per-point SHOT LRF + log-map + histogram (all f32) ----------------

__global__ __launch_bounds__(64) void shot_kernel(const float* __restrict__ coords,
                                                  const float* __restrict__ radius_arr,
                                                  const float* __restrict__ nbrD,
                                                  const int* __restrict__ nbrI,
                                                  float* __restrict__ out) {
  int g = blockIdx.x * 64 + threadIdx.x;
  if (g >= NTOT) return;
  int b = g >> 12;
  int p = g & (NPTS - 1);
  float radius = radius_arr[b];
  const float* cb = coords + (size_t)b * NPTS * 3;
  float xi = cb[p * 3 + 0], yi = cb[p * 3 + 1], zi = cb[p * 3 + 2];
  float fill = 2.0f * radius / sqrtf(3.0f);

  // coalesced transposed reads of neighbor ids/dists
  int jj[NNB];
  float dd[NNB];
#pragma unroll
  for (int k = 0; k < NNB; ++k) {
    jj[k] = nbrI[(size_t)k * NTOT + g];
    dd[k] = nbrD[(size_t)k * NTOT + g];
  }

  float nbx[NNB], nby[NNB], nbz[NNB], dk[NNB];
#pragma unroll
  for (int k = 0; k < NNB; ++k) {
    int j = jj[k];
    float nx, ny, nz;
    if (dd[k] > radius) { nx = fill; ny = fill; nz = fill; }
    else {
      nx = cb[j * 3 + 0] - xi;
      ny = cb[j * 3 + 1] - yi;
      nz = cb[j * 3 + 2] - zi;
    }
    nbx[k] = nx; nby[k] = ny; nbz[k] = nz;
    dk[k] = sqrtf((nx * nx + ny * ny) + nz * nz);
  }

  float wsum = 0.0f;
  float c00 = 0, c11 = 0, c22 = 0;
  float c01 = 0, c10 = 0, c02 = 0, c20 = 0, c12 = 0, c21 = 0;
  for (int k = 0; k < NNB; ++k) {
    float w = fmaxf(radius - dk[k], 0.0f);
    wsum += w;
    float wx = w * nbx[k], wy = w * nby[k], wz = w * nbz[k];
    c00 += wx * nbx[k]; c01 += wx * nby[k]; c02 += wx * nbz[k];
    c10 += wy * nbx[k]; c11 += wy * nby[k]; c12 += wy * nbz[k];
    c20 += wz * nbx[k]; c21 += wz * nby[k]; c22 += wz * nbz[k];
  }
  float den = wsum + 1e-12f;
  float a00 = c00 / den, a11 = c11 / den, a22 = c22 / den;
  float a01 = c01 / den, a10 = c10 / den;
  float a02 = c02 / den, a20 = c20 / den;
  float a12 = c12 / den, a21 = c21 / den;
  float A10 = 0.5f * (a01 + a10);
  float A20 = 0.5f * (a02 + a20);
  float A21 = 0.5f * (a12 + a21);

  float V[3][3];
  eigh3f(a00, A10, A20, a11, A21, a22, V);

  float xax0 = V[0][2], xax1 = V[1][2], xax2 = V[2][2];
  float zax0 = V[0][0], zax1 = V[1][0], zax2 = V[2][0];

  {
    int pos = 0, neg = 0;
    for (int k = 0; k < NNB; ++k) {
      float dt = (nbx[k] * xax0 + nby[k] * xax1) + nbz[k] * xax2;
      if (dt >= 0.0f) pos++; else neg++;
    }
    if (pos < neg) { xax0 = -xax0; xax1 = -xax1; xax2 = -xax2; }
  }
  {
    int pos = 0, neg = 0;
    for (int k = 0; k < NNB; ++k) {
      float dt = (nbx[k] * zax0 + nby[k] * zax1) + nbz[k] * zax2;
      if (dt >= 0.0f) pos++; else neg++;
    }
    if (pos < neg) { zax0 = -zax0; zax1 = -zax1; zax2 = -zax2; }
  }
  float yax0 = zax1 * xax2 - zax2 * xax1;
  float yax1 = zax2 * xax0 - zax0 * xax2;
  float yax2 = zax0 * xax1 - zax1 * xax0;

  float hist[NBINS * NBINS];
  for (int k = 0; k < NBINS * NBINS; ++k) hist[k] = 0.0f;
  float stp = 2.0f * radius / (float)NBINS;
  for (int k = 0; k < NNB; ++k) {
    float u = (nbx[k] * xax0 + nby[k] * xax1) + nbz[k] * xax2;
    float v = (nbx[k] * yax0 + nby[k] * yax1) + nbz[k] * yax2;
    float pn = sqrtf(u * u + v * v);
    float sc = dk[k] / (pn + 1e-12f);
    float pu = u * sc, pv = v * sc;
    float bxf = floorf((pu + radius) / stp);
    float byf = floorf((pv + radius) / stp);
    if (bxf >= 0.0f && bxf < (float)NBINS && byf >= 0.0f && byf < (float)NBINS) {
      int bx = (int)bxf, by = (int)byf;
      hist[by * NBINS + bx] += 1.0f;
    }
  }
  float cvals[NBINS];
  for (int i = 0; i < NBINS; ++i) cvals[i] = ((float)i * stp - radius) + 0.5f * stp;
  float nrm2 = 0.0f;
  for (int i = 0; i < NBINS; ++i) {
    for (int j = 0; j < NBINS; ++j) {
      float wgt = radius - sqrtf(cvals[i] * cvals[i] + cvals[j] * cvals[j]);
      float h = hist[i * NBINS + j] * wgt;
      hist[i * NBINS + j] = h;
      nrm2 += h * h;
    }
  }
  float nrm = sqrtf(nrm2);
  for (int k = 0; k < NBINS * NBINS; ++k) {
    out[(size_t)g * (NBINS * NBINS) + k] = hist[k] / nrm;
  }
}

// ---------------- Launch ----------------

extern "C" void kernel_launch(void* const* d_in, const int* in_sizes, int n_in,
                              void* d_out, int out_size, void* d_ws, size_t ws_size,
                              hipStream_t stream) {
  const float* coords = (const float*)d_in[0];
  float* out = (float*)d_out;

  float* wsf = (float*)d_ws;
  float* radius = wsf;                            // 4 floats (+pad to 8)
  float* d16 = wsf + 8;                           // 16384 floats
  float* nbrD = wsf + 8 + (size_t)NTOT;           // [NNB][NTOT] floats
  int* nbrI = (int*)(nbrD + (size_t)NNB * NTOT);  // [NNB][NTOT] ints

  knn_kernel<<<NTOT / 16, 1024, 0, stream>>>(coords, nbrD, nbrI, d16);
  radius_kernel<<<NBATCH, 64, 0, stream>>>(d16, radius);
  shot_kernel<<<NTOT / 64, 64, 0, stream>>>(coords, radius, nbrD, nbrI, out);
}

// Round 13
// 124.627 us; speedup vs baseline: 1.1307x; 1.0388x over previous
//
#include <hip/hip_runtime.h>
#include <math.h>

// Match XLA/LAPACK f32 rounding: no FMA contraction anywhere in this file.
#pragma clang fp contract(off)

#define NPTS 4096
#define NBATCH 4
#define NTOT (NBATCH * NPTS)
#define NNB 20
#define NBINS 5
#define LTOP 7    // per-lane top-list size; P(lane holds >=8 of top-20) ~ 5e-4 total

// f32 LAPACK machine constants
#define SEPS    5.9604644775390625e-8f   // SLAMCH('E') = 2^-24
#define SSAFMIN 1.17549435e-38f          // SLAMCH('S') = 2^-126

// ---------------- LAPACK helpers (f32, faithful to reference LAPACK >= 3.10) ----------------

__device__ __forceinline__ float f_signf(float a, float b) {
  return __builtin_signbit(b) ? -fabsf(a) : fabsf(a);
}

__device__ float slapy2_(float x, float y) {
  float xa = fabsf(x), ya = fabsf(y);
  float w = fmaxf(xa, ya), z = fminf(xa, ya);
  if (z == 0.0f) return w;
  float t = z / w;
  return w * sqrtf(1.0f + t * t);
}

// LAPACK >= 3.10 slartg (c = |f|/d >= 0, r = sign(f)*d); unscaled path (values are moderate)
__device__ void slartg_(float f, float g, float* c, float* s, float* r) {
  if (g == 0.0f) {
    *c = 1.0f; *s = 0.0f; *r = f;
  } else if (f == 0.0f) {
    *c = 0.0f; *s = __builtin_signbit(g) ? -1.0f : 1.0f; *r = fabsf(g);
  } else {
    float f1 = fabsf(f);
    float d = sqrtf(f * f + g * g);
    *c = f1 / d;
    float rr = __builtin_signbit(f) ? -d : d;
    *r = rr;
    *s = g / rr;
  }
}

__device__ void slaev2_(float a, float b, float c,
                        float* rt1, float* rt2, float* cs1, float* sn1) {
  float sm = a + c;
  float df = a - c;
  float adf = fabsf(df);
  float tb = b + b;
  float ab = fabsf(tb);
  float acmx, acmn;
  if (fabsf(a) > fabsf(c)) { acmx = a; acmn = c; } else { acmx = c; acmn = a; }
  float rt;
  if (adf > ab)      { float t = ab / adf; rt = adf * sqrtf(1.0f + t * t); }
  else if (adf < ab) { float t = adf / ab; rt = ab * sqrtf(1.0f + t * t); }
  else               { rt = ab * sqrtf(2.0f); }
  int sgn1;
  if (sm < 0.0f) {
    *rt1 = 0.5f * (sm - rt); sgn1 = -1;
    *rt2 = (acmx / *rt1) * acmn - (b / *rt1) * b;
  } else if (sm > 0.0f) {
    *rt1 = 0.5f * (sm + rt); sgn1 = 1;
    *rt2 = (acmx / *rt1) * acmn - (b / *rt1) * b;
  } else {
    *rt1 = 0.5f * rt; *rt2 = -0.5f * rt; sgn1 = 1;
  }
  float cs; int sgn2;
  if (df >= 0.0f) { cs = df + rt; sgn2 = 1; }
  else            { cs = df - rt; sgn2 = -1; }
  float acs = fabsf(cs);
  float csv, snv;
  if (acs > ab) {
    float ct = -tb / cs;
    snv = 1.0f / sqrtf(1.0f + ct * ct);
    csv = ct * snv;
  } else {
    if (ab == 0.0f) { csv = 1.0f; snv = 0.0f; }
    else {
      float tn = -cs / tb;
      csv = 1.0f / sqrtf(1.0f + tn * tn);
      snv = tn * csv;
    }
  }
  if (sgn1 == sgn2) { float tn = csv; csv = -snv; snv = tn; }
  *cs1 = csv; *sn1 = snv;
}

// SSTEQR('I', n=3) faithful port
__device__ void ssteqr3(float* d, float* e, float Z[3][3]) {
  const int n = 3;
  const float eps = SEPS;
  const float eps2 = SEPS * SEPS;
  const float safmin = SSAFMIN;
  const int nmaxit = 90;
  int jtot = 0;
  int l1 = 1;
  int l = 0, lsv = 0, lend = 0, lendsv = 0, m = 0, mm = 0;
  float p = 0, g = 0, r = 0, c = 0, s = 0, f = 0, bb = 0, rt1 = 0, rt2 = 0;
  float anorm = 0, tst = 0;
  float wc[2], wsn[2];

L10:
  if (l1 > n) goto L160;
  if (l1 > 1) e[l1 - 2] = 0.0f;
  if (l1 <= n - 1) {
    for (m = l1; m <= n - 1; ++m) {
      tst = fabsf(e[m - 1]);
      if (tst == 0.0f) goto L30;
      if (tst <= (sqrtf(fabsf(d[m - 1])) * sqrtf(fabsf(d[m]))) * eps) {
        e[m - 1] = 0.0f;
        goto L30;
      }
    }
  }
  m = n;
L30:
  l = l1; lsv = l; lend = m; lendsv = lend; l1 = m + 1;
  if (lend == l) goto L10;
  anorm = 0.0f;
  for (int i = l; i <= lend; ++i) anorm = fmaxf(anorm, fabsf(d[i - 1]));
  for (int i = l; i <= lend - 1; ++i) anorm = fmaxf(anorm, fabsf(e[i - 1]));
  if (anorm == 0.0f) goto L10;
  if (fabsf(d[lend - 1]) < fabsf(d[l - 1])) { lend = lsv; l = lendsv; }

  if (lend > l) {
L40:
    if (l != lend) {
      for (m = l; m <= lend - 1; ++m) {
        tst = e[m - 1] * e[m - 1];
        if (tst <= (eps2 * fabsf(d[m - 1])) * fabsf(d[m]) + safmin) goto L60;
      }
    }
    m = lend;
L60:
    if (m < lend) e[m - 1] = 0.0f;
    p = d[l - 1];
    if (m == l) goto L80;
    if (m == l + 1) {
      slaev2_(d[l - 1], e[l - 1], d[l], &rt1, &rt2, &c, &s);
      for (int i = 0; i < n; ++i) {
        float tz = Z[i][l];
        Z[i][l]     = c * tz - s * Z[i][l - 1];
        Z[i][l - 1] = s * tz + c * Z[i][l - 1];
      }
      d[l - 1] = rt1; d[l] = rt2; e[l - 1] = 0.0f;
      l += 2;
      if (l <= lend) goto L40;
      goto L140;
    }
    if (jtot == nmaxit) goto L140;
    jtot++;
    g = (d[l] - p) / (2.0f * e[l - 1]);
    r = slapy2_(g, 1.0f);
    g = d[m - 1] - p + e[l - 1] / (g + f_signf(r, g));
    s = 1.0f; c = 1.0f; p = 0.0f;
    for (int i = m - 1; i >= l; --i) {
      f = s * e[i - 1];
      bb = c * e[i - 1];
      slartg_(g, f, &c, &s, &r);
      if (i != m - 1) e[i] = r;
      g = d[i] - p;
      r = (d[i - 1] - g) * s + 2.0f * c * bb;
      p = s * r;
      d[i] = g + p;
      g = c * r - bb;
      wc[i - 1] = c; wsn[i - 1] = -s;
    }
    mm = m - l + 1;
    for (int j = mm - 1; j >= 1; --j) {
      float ct = wc[l + j - 2], st = wsn[l + j - 2];
      for (int i = 0; i < n; ++i) {
        float tz = Z[i][l + j - 1];
        Z[i][l + j - 1] = ct * tz - st * Z[i][l + j - 2];
        Z[i][l + j - 2] = st * tz + ct * Z[i][l + j - 2];
      }
    }
    d[l - 1] -= p;
    e[l - 1] = g;
    goto L40;
L80:
    d[l - 1] = p;
    l++;
    if (l <= lend) goto L40;
    goto L140;
  } else {
L90:
    if (l != lend) {
      for (m = l; m >= lend + 1; --m) {
        tst = e[m - 2] * e[m - 2];
        if (tst <= (eps2 * fabsf(d[m - 1])) * fabsf(d[m - 2]) + safmin) goto L110;
      }
    }
    m = lend;
L110:
    if (m > lend) e[m - 2] = 0.0f;
    p = d[l - 1];
    if (m == l) goto L130;
    if (m == l - 1) {
      slaev2_(d[l - 2], e[l - 2], d[l - 1], &rt1, &rt2, &c, &s);
      for (int i = 0; i < n; ++i) {
        float tz = Z[i][l - 1];
        Z[i][l - 1] = c * tz - s * Z[i][l - 2];
        Z[i][l - 2] = s * tz + c * Z[i][l - 2];
      }
      d[l - 2] = rt1; d[l - 1] = rt2; e[l - 2] = 0.0f;
      l -= 2;
      if (l >= lend) goto L90;
      goto L140;
    }
    if (jtot == nmaxit) goto L140;
    jtot++;
    g = (d[l - 2] - p) / (2.0f * e[l - 2]);
    r = slapy2_(g, 1.0f);
    g = d[m - 1] - p + e[l - 2] / (g + f_signf(r, g));
    s = 1.0f; c = 1.0f; p = 0.0f;
    for (int i = m; i <= l - 1; ++i) {
      f = s * e[i - 1];
      bb = c * e[i - 1];
      slartg_(g, f, &c, &s, &r);
      if (i != m) e[i - 2] = r;
      g = d[i - 1] - p;
      r = (d[i] - g) * s + 2.0f * c * bb;
      p = s * r;
      d[i - 1] = g + p;
      g = c * r - bb;
      wc[i - 1] = c; wsn[i - 1] = s;
    }
    mm = l - m + 1;
    for (int j = 1; j <= mm - 1; ++j) {
      float ct = wc[m + j - 2], st = wsn[m + j - 2];
      for (int i = 0; i < n; ++i) {
        float tz = Z[i][m + j - 1];
        Z[i][m + j - 1] = ct * tz - st * Z[i][m + j - 2];
        Z[i][m + j - 2] = st * tz + ct * Z[i][m + j - 2];
      }
    }
    d[l - 1] -= p;
    e[l - 2] = g;
    goto L90;
L130:
    d[l - 1] = p;
    l--;
    if (l >= lend) goto L90;
    goto L140;
  }
L140:
  if (jtot < nmaxit) goto L10;
  goto L160;
L160:
  for (int ii = 2; ii <= n; ++ii) {
    int i = ii - 1, k = i;
    float pp = d[i - 1];
    for (int j = ii; j <= n; ++j)
      if (d[j - 1] < pp) { k = j; pp = d[j - 1]; }
    if (k != i) {
      d[k - 1] = d[i - 1]; d[i - 1] = pp;
      for (int row = 0; row < n; ++row) {
        float t2 = Z[row][i - 1]; Z[row][i - 1] = Z[row][k - 1]; Z[row][k - 1] = t2;
      }
    }
  }
}

// ssyevd('V','L') for 3x3: ssytd2 -> ssteqr('I') -> sormtr.
__device__ void eigh3f(float A00, float A10, float A20, float A11, float A21, float A22,
                       float V[3][3]) {
  float d[3], e[2];
  float taui, v2, beta;
  float alpha = A10;
  float xnorm = fabsf(A20);
  if (xnorm == 0.0f) {
    taui = 0.0f; beta = alpha; v2 = 0.0f;
  } else {
    beta = -f_signf(slapy2_(alpha, xnorm), alpha);
    taui = (beta - alpha) / beta;
    v2 = A20 * (1.0f / (alpha - beta));
  }
  float a11 = A11, a21 = A21, a22 = A22;
  if (taui != 0.0f) {
    float w0 = taui * (a11 + a21 * v2);
    float w1 = taui * (a21 + a22 * v2);
    float al = -0.5f * taui * (w0 + w1 * v2);
    w0 += al; w1 += al * v2;
    a11 -= 2.0f * w0;
    a21 -= (v2 * w0 + w1);
    a22 -= 2.0f * (v2 * w1);
  }
  d[0] = A00; d[1] = a11; d[2] = a22;
  e[0] = beta; e[1] = a21;

  float Z[3][3] = {{1.0f, 0.0f, 0.0f}, {0.0f, 1.0f, 0.0f}, {0.0f, 0.0f, 1.0f}};
  ssteqr3(d, e, Z);

  for (int k = 0; k < 3; ++k) {
    float t = taui * (Z[1][k] + v2 * Z[2][k]);
    Z[1][k] -= t;
    Z[2][k] -= t * v2;
  }
  for (int i = 0; i < 3; ++i)
    for (int k = 0; k < 3; ++k) V[i][k] = Z[i][k];
}

// wave64 u32 min-reduce via DPP (row_shr 1/2/4/8 + row_bcast15/31); result valid in lane 63.
__device__ __forceinline__ unsigned wave_min_dpp(unsigned v) {
  unsigned t;
  t = (unsigned)__builtin_amdgcn_update_dpp(-1, (int)v, 0x111, 0xf, 0xf, false); v = t < v ? t : v;
  t = (unsigned)__builtin_amdgcn_update_dpp(-1, (int)v, 0x112, 0xf, 0xf, false); v = t < v ? t : v;
  t = (unsigned)__builtin_amdgcn_update_dpp(-1, (int)v, 0x114, 0xf, 0xf, false); v = t < v ? t : v;
  t = (unsigned)__builtin_amdgcn_update_dpp(-1, (int)v, 0x118, 0xf, 0xf, false); v = t < v ? t : v;
  t = (unsigned)__builtin_amdgcn_update_dpp(-1, (int)v, 0x142, 0xa, 0xf, false); v = t < v ? t : v;
  t = (unsigned)__builtin_amdgcn_update_dpp(-1, (int)v, 0x143, 0xc, 0xf, false); v = t < v ? t : v;
  return v;
}

// ---------------- Kernel A: wave-per-point KNN (FROZEN at R12 best: 72.3 us) ----------------
// Composite sort key: f64 bit-concat hi=|d2| f32 bits, lo=idx. For positive finite
// doubles, f64 order == lex unsigned (hi,lo) == (key, idx) == reference stable argsort
// of sqrt(|d2|). Insert = straight-line closed-form min/max network.
// Extraction: two-stage (hi,lo) u32 DPP min; owner unique (idx embedded).

__global__ __launch_bounds__(1024, 8) void knn_kernel(const float* __restrict__ coords,
                                                      float* __restrict__ nbrD,
                                                      int* __restrict__ nbrI,
                                                      float* __restrict__ d16) {
  __shared__ float4 scs[NPTS];     // 64 KB: {x, y, z, sq}
  int tid = threadIdx.x;
  int wid = tid >> 6;
  int lane = tid & 63;
  int P = blockIdx.x * 16 + wid;   // 16 | 4096, no batch crossing
  int b = P >> 12;
  int p = P & (NPTS - 1);
  const float* cb = coords + (size_t)b * NPTS * 3;

  for (int i = tid; i < NPTS; i += 1024) {
    float x = cb[3 * i + 0], y = cb[3 * i + 1], z = cb[3 * i + 2];
    float sq = (x * x + y * y) + z * z;   // exact ref expression order
    scs[i] = make_float4(x, y, z, sq);
  }
  __syncthreads();

  float4 ci = scs[p];
  float xi = ci.x, yi = ci.y, zi = ci.z, sqi = ci.w;

  const double INF = __hiloint2double(0x7FF00000, 0);   // +inf sentinel (> any composite)
  double L[LTOP];
#pragma unroll
  for (int t = 0; t < LTOP; ++t) L[t] = INF;

#pragma unroll 8
  for (int k = 0; k < NPTS / 64; ++k) {
    int j = k * 64 + lane;
    float4 cj = scs[j];                       // one ds_read_b128
    float dot = (xi * cj.x + yi * cj.y) + zi * cj.z;
    float d2 = (sqi - 2.0f * dot) + cj.w;     // exact ref expression order
    unsigned kb = __float_as_uint(d2) & 0x7FFFFFFFu;   // |d2| bits
    double cur = __hiloint2double((int)kb, j);         // bit-concat composite key
    // sorted-insert min/max network (maxes from OLD L values)
    double m1 = fmax(cur, L[0]);
    double m2 = fmax(cur, L[1]);
    double m3 = fmax(cur, L[2]);
    double m4 = fmax(cur, L[3]);
    double m5 = fmax(cur, L[4]);
    double m6 = fmax(cur, L[5]);
    L[0] = fmin(L[0], cur);
    L[1] = fmin(L[1], m1);
    L[2] = fmin(L[2], m2);
    L[3] = fmin(L[3], m3);
    L[4] = fmin(L[4], m4);
    L[5] = fmin(L[5], m5);
    L[6] = fmin(L[6], m6);
  }

  unsigned resHi = 0, resLo = 0;
  for (int r = 0; r < NNB; ++r) {
    unsigned hi0 = (unsigned)__double2hiint(L[0]);
    unsigned lo0 = (unsigned)__double2loint(L[0]);
    unsigned gh = wave_min_dpp(hi0);
    gh = (unsigned)__builtin_amdgcn_readlane((int)gh, 63);
    unsigned lom = (hi0 == gh) ? lo0 : 0xFFFFFFFFu;
    unsigned gl = wave_min_dpp(lom);
    gl = (unsigned)__builtin_amdgcn_readlane((int)gl, 63);
    bool mine = (hi0 == gh) && (lo0 == gl);   // idx embedded -> unique owner
#pragma unroll
    for (int t = 0; t < LTOP - 1; ++t) L[t] = mine ? L[t + 1] : L[t];
    L[LTOP - 1] = mine ? INF : L[LTOP - 1];
    if (lane == r) { resHi = gh; resLo = gl; }
  }

  if (lane < NNB) {
    float dist = sqrtf(__uint_as_float(resHi));   // hi word IS the f32 |d2| key bits
    nbrD[(size_t)lane * NTOT + P] = dist;         // transposed [NNB][NTOT]
    nbrI[(size_t)lane * NTOT + P] = (int)resLo;   // lo word IS the index
    if (lane == 16) d16[P] = dist;                // dsort[:,16]
  }
}

// ---------------- Kernel C: fused radius + per-point SHOT LRF + log-map + histogram ----------------
// Radius computed redundantly per block with the EXACT same LDS-staged sequential f32
// chain as the old radius_kernel (bit-identical result, all blocks agree). All global
// gather loads (nbrI/nbrD/neighbor coords) are issued BEFORE the 16k-cycle add chain so
// their HBM/L2 latency hides under it (this kernel runs at 1 wave/SIMD: no TLP).

__global__ __launch_bounds__(64) void shot_kernel(const float* __restrict__ coords,
                                                  const float* __restrict__ d16,
                                                  const float* __restrict__ nbrD,
                                                  const int* __restrict__ nbrI,
                                                  float* __restrict__ out) {
  __shared__ float buf[NPTS];   // 16 KB: d16 of this block's batch
  int lane = threadIdx.x;
  int g = blockIdx.x * 64 + lane;       // grid exact: 256 blocks x 64
  int b = g >> 12;
  int p = g & (NPTS - 1);
  const float* cb = coords + (size_t)b * NPTS * 3;

  // stage d16 (coalesced)
  for (int i = lane; i < NPTS; i += 64) buf[i] = d16[(size_t)b * NPTS + i];

  // issue all gathers before the radius chain (latency hides under it)
  int jj[NNB];
  float dd[NNB];
#pragma unroll
  for (int k = 0; k < NNB; ++k) {
    jj[k] = nbrI[(size_t)k * NTOT + g];   // coalesced
    dd[k] = nbrD[(size_t)k * NTOT + g];   // coalesced
  }
  float gx[NNB], gy[NNB], gz[NNB];
#pragma unroll
  for (int k = 0; k < NNB; ++k) {
    int j = jj[k];
    gx[k] = cb[j * 3 + 0];                // scattered gathers, in flight during chain
    gy[k] = cb[j * 3 + 1];
    gz[k] = cb[j * 3 + 2];
  }
  float xi = cb[p * 3 + 0], yi = cb[p * 3 + 1], zi = cb[p * 3 + 2];

  __syncthreads();
  // bit-identical sequential f32 radius chain (same order as reference emulation)
  float s = 0.0f;
  for (int k = 0; k < NPTS; ++k) s += buf[k];   // same-addr LDS broadcast reads
  float radius = s / 4096.0f;

  float fill = 2.0f * radius / sqrtf(3.0f);

  float nbx[NNB], nby[NNB], nbz[NNB], dk[NNB];
#pragma unroll
  for (int k = 0; k < NNB; ++k) {
    float nx, ny, nz;
    if (dd[k] > radius) { nx = fill; ny = fill; nz = fill; }
    else {
      nx = gx[k] - xi;
      ny = gy[k] - yi;
      nz = gz[k] - zi;
    }
    nbx[k] = nx; nby[k] = ny; nbz[k] = nz;
    dk[k] = sqrtf((nx * nx + ny * ny) + nz * nz);
  }

  float wsum = 0.0f;
  float c00 = 0, c11 = 0, c22 = 0;
  float c01 = 0, c10 = 0, c02 = 0, c20 = 0, c12 = 0, c21 = 0;
  for (int k = 0; k < NNB; ++k) {
    float w = fmaxf(radius - dk[k], 0.0f);
    wsum += w;
    float wx = w * nbx[k], wy = w * nby[k], wz = w * nbz[k];
    c00 += wx * nbx[k]; c01 += wx * nby[k]; c02 += wx * nbz[k];
    c10 += wy * nbx[k]; c11 += wy * nby[k]; c12 += wy * nbz[k];
    c20 += wz * nbx[k]; c21 += wz * nby[k]; c22 += wz * nbz[k];
  }
  float den = wsum + 1e-12f;
  float a00 = c00 / den, a11 = c11 / den, a22 = c22 / den;
  float a01 = c01 / den, a10 = c10 / den;
  float a02 = c02 / den, a20 = c20 / den;
  float a12 = c12 / den, a21 = c21 / den;
  float A10 = 0.5f * (a01 + a10);
  float A20 = 0.5f * (a02 + a20);
  float A21 = 0.5f * (a12 + a21);

  float V[3][3];
  eigh3f(a00, A10, A20, a11, A21, a22, V);

  float xax0 = V[0][2], xax1 = V[1][2], xax2 = V[2][2];
  float zax0 = V[0][0], zax1 = V[1][0], zax2 = V[2][0];

  {
    int pos = 0, neg = 0;
    for (int k = 0; k < NNB; ++k) {
      float dt = (nbx[k] * xax0 + nby[k] * xax1) + nbz[k] * xax2;
      if (dt >= 0.0f) pos++; else neg++;
    }
    if (pos < neg) { xax0 = -xax0; xax1 = -xax1; xax2 = -xax2; }
  }
  {
    int pos = 0, neg = 0;
    for (int k = 0; k < NNB; ++k) {
      float dt = (nbx[k] * zax0 + nby[k] * zax1) + nbz[k] * zax2;
      if (dt >= 0.0f) pos++; else neg++;
    }
    if (pos < neg) { zax0 = -zax0; zax1 = -zax1; zax2 = -zax2; }
  }
  float yax0 = zax1 * xax2 - zax2 * xax1;
  float yax1 = zax2 * xax0 - zax0 * xax2;
  float yax2 = zax0 * xax1 - zax1 * xax0;

  float hist[NBINS * NBINS];
  for (int k = 0; k < NBINS * NBINS; ++k) hist[k] = 0.0f;
  float stp = 2.0f * radius / (float)NBINS;
  for (int k = 0; k < NNB; ++k) {
    float u = (nbx[k] * xax0 + nby[k] * xax1) + nbz[k] * xax2;
    float v = (nbx[k] * yax0 + nby[k] * yax1) + nbz[k] * yax2;
    float pn = sqrtf(u * u + v * v);
    float sc = dk[k] / (pn + 1e-12f);
    float pu = u * sc, pv = v * sc;
    float bxf = floorf((pu + radius) / stp);
    float byf = floorf((pv + radius) / stp);
    if (bxf >= 0.0f && bxf < (float)NBINS && byf >= 0.0f && byf < (float)NBINS) {
      int bx = (int)bxf, by = (int)byf;
      hist[by * NBINS + bx] += 1.0f;
    }
  }
  float cvals[NBINS];
  for (int i = 0; i < NBINS; ++i) cvals[i] = ((float)i * stp - radius) + 0.5f * stp;
  float nrm2 = 0.0f;
  for (int i = 0; i < NBINS; ++i) {
    for (int j = 0; j < NBINS; ++j) {
      float wgt = radius - sqrtf(cvals[i] * cvals[i] + cvals[j] * cvals[j]);
      float h = hist[i * NBINS + j] * wgt;
      hist[i * NBINS + j] = h;
      nrm2 += h * h;
    }
  }
  float nrm = sqrtf(nrm2);
  for (int k = 0; k < NBINS * NBINS; ++k) {
    out[(size_t)g * (NBINS * NBINS) + k] = hist[k] / nrm;
  }
}

// ---------------- Launch ----------------

extern "C" void kernel_launch(void* const* d_in, const int* in_sizes, int n_in,
                              void* d_out, int out_size, void* d_ws, size_t ws_size,
                              hipStream_t stream) {
  const float* coords = (const float*)d_in[0];
  float* out = (float*)d_out;

  float* wsf = (float*)d_ws;
  float* d16 = wsf + 8;                           // 16384 floats
  float* nbrD = wsf + 8 + (size_t)NTOT;           // [NNB][NTOT] floats
  int* nbrI = (int*)(nbrD + (size_t)NNB * NTOT);  // [NNB][NTOT] ints

  knn_kernel<<<NTOT / 16, 1024, 0, stream>>>(coords, nbrD, nbrI, d16);
  shot_kernel<<<NTOT / 64, 64, 0, stream>>>(coords, d16, nbrD, nbrI, out);
}

// Round 14
// 116.955 us; speedup vs baseline: 1.2048x; 1.0656x over previous
//
#include <hip/hip_runtime.h>
#include <math.h>

// Match XLA/LAPACK f32 rounding: no FMA contraction anywhere in this file.
#pragma clang fp contract(off)

#define NPTS 4096
#define NBATCH 4
#define NTOT (NBATCH * NPTS)
#define NNB 20
#define NBINS 5
#define LTOP 7    // per-lane top-list size; P(lane holds >=8 of top-20) ~ 5e-4 total

// f32 LAPACK machine constants
#define SEPS    5.9604644775390625e-8f   // SLAMCH('E') = 2^-24
#define SSAFMIN 1.17549435e-38f          // SLAMCH('S') = 2^-126

// ---------------- LAPACK helpers (f32, faithful to reference LAPACK >= 3.10) ----------------

__device__ __forceinline__ float f_signf(float a, float b) {
  return __builtin_signbit(b) ? -fabsf(a) : fabsf(a);
}

__device__ float slapy2_(float x, float y) {
  float xa = fabsf(x), ya = fabsf(y);
  float w = fmaxf(xa, ya), z = fminf(xa, ya);
  if (z == 0.0f) return w;
  float t = z / w;
  return w * sqrtf(1.0f + t * t);
}

// LAPACK >= 3.10 slartg (c = |f|/d >= 0, r = sign(f)*d); unscaled path (values are moderate)
__device__ void slartg_(float f, float g, float* c, float* s, float* r) {
  if (g == 0.0f) {
    *c = 1.0f; *s = 0.0f; *r = f;
  } else if (f == 0.0f) {
    *c = 0.0f; *s = __builtin_signbit(g) ? -1.0f : 1.0f; *r = fabsf(g);
  } else {
    float f1 = fabsf(f);
    float d = sqrtf(f * f + g * g);
    *c = f1 / d;
    float rr = __builtin_signbit(f) ? -d : d;
    *r = rr;
    *s = g / rr;
  }
}

__device__ void slaev2_(float a, float b, float c,
                        float* rt1, float* rt2, float* cs1, float* sn1) {
  float sm = a + c;
  float df = a - c;
  float adf = fabsf(df);
  float tb = b + b;
  float ab = fabsf(tb);
  float acmx, acmn;
  if (fabsf(a) > fabsf(c)) { acmx = a; acmn = c; } else { acmx = c; acmn = a; }
  float rt;
  if (adf > ab)      { float t = ab / adf; rt = adf * sqrtf(1.0f + t * t); }
  else if (adf < ab) { float t = adf / ab; rt = ab * sqrtf(1.0f + t * t); }
  else               { rt = ab * sqrtf(2.0f); }
  int sgn1;
  if (sm < 0.0f) {
    *rt1 = 0.5f * (sm - rt); sgn1 = -1;
    *rt2 = (acmx / *rt1) * acmn - (b / *rt1) * b;
  } else if (sm > 0.0f) {
    *rt1 = 0.5f * (sm + rt); sgn1 = 1;
    *rt2 = (acmx / *rt1) * acmn - (b / *rt1) * b;
  } else {
    *rt1 = 0.5f * rt; *rt2 = -0.5f * rt; sgn1 = 1;
  }
  float cs; int sgn2;
  if (df >= 0.0f) { cs = df + rt; sgn2 = 1; }
  else            { cs = df - rt; sgn2 = -1; }
  float acs = fabsf(cs);
  float csv, snv;
  if (acs > ab) {
    float ct = -tb / cs;
    snv = 1.0f / sqrtf(1.0f + ct * ct);
    csv = ct * snv;
  } else {
    if (ab == 0.0f) { csv = 1.0f; snv = 0.0f; }
    else {
      float tn = -cs / tb;
      csv = 1.0f / sqrtf(1.0f + tn * tn);
      snv = tn * csv;
    }
  }
  if (sgn1 == sgn2) { float tn = csv; csv = -snv; snv = tn; }
  *cs1 = csv; *sn1 = snv;
}

// Per-lane LDS workspace accessors: element i of this lane lives at w[i*64].
// Layout: d[0..2]=0..2, e[0..1]=3..4, Z[i][j]=5+i*3+j, wc[0..1]=14..15, wsn[0..1]=16..17.
#define DD(i)    w[(i) * 64]
#define EE(i)    w[(3 + (i)) * 64]
#define ZZ(i, j) w[(5 + (i) * 3 + (j)) * 64]
#define CC(i)    w[(14 + (i)) * 64]
#define SN(i)    w[(16 + (i)) * 64]

// SSTEQR('I', n=3) faithful port; arrays in LDS (runtime-indexed -> scratch otherwise)
__device__ void ssteqr3_lds(float* w) {
  const int n = 3;
  const float eps = SEPS;
  const float eps2 = SEPS * SEPS;
  const float safmin = SSAFMIN;
  const int nmaxit = 90;
  int jtot = 0;
  int l1 = 1;
  int l = 0, lsv = 0, lend = 0, lendsv = 0, m = 0, mm = 0;
  float p = 0, g = 0, r = 0, c = 0, s = 0, f = 0, bb = 0, rt1 = 0, rt2 = 0;
  float anorm = 0, tst = 0;

L10:
  if (l1 > n) goto L160;
  if (l1 > 1) EE(l1 - 2) = 0.0f;
  if (l1 <= n - 1) {
    for (m = l1; m <= n - 1; ++m) {
      tst = fabsf(EE(m - 1));
      if (tst == 0.0f) goto L30;
      if (tst <= (sqrtf(fabsf(DD(m - 1))) * sqrtf(fabsf(DD(m)))) * eps) {
        EE(m - 1) = 0.0f;
        goto L30;
      }
    }
  }
  m = n;
L30:
  l = l1; lsv = l; lend = m; lendsv = lend; l1 = m + 1;
  if (lend == l) goto L10;
  anorm = 0.0f;
  for (int i = l; i <= lend; ++i) anorm = fmaxf(anorm, fabsf(DD(i - 1)));
  for (int i = l; i <= lend - 1; ++i) anorm = fmaxf(anorm, fabsf(EE(i - 1)));
  if (anorm == 0.0f) goto L10;
  if (fabsf(DD(lend - 1)) < fabsf(DD(l - 1))) { lend = lsv; l = lendsv; }

  if (lend > l) {
L40:
    if (l != lend) {
      for (m = l; m <= lend - 1; ++m) {
        tst = EE(m - 1) * EE(m - 1);
        if (tst <= (eps2 * fabsf(DD(m - 1))) * fabsf(DD(m)) + safmin) goto L60;
      }
    }
    m = lend;
L60:
    if (m < lend) EE(m - 1) = 0.0f;
    p = DD(l - 1);
    if (m == l) goto L80;
    if (m == l + 1) {
      slaev2_(DD(l - 1), EE(l - 1), DD(l), &rt1, &rt2, &c, &s);
      for (int i = 0; i < n; ++i) {
        float tz = ZZ(i, l);
        ZZ(i, l)     = c * tz - s * ZZ(i, l - 1);
        ZZ(i, l - 1) = s * tz + c * ZZ(i, l - 1);
      }
      DD(l - 1) = rt1; DD(l) = rt2; EE(l - 1) = 0.0f;
      l += 2;
      if (l <= lend) goto L40;
      goto L140;
    }
    if (jtot == nmaxit) goto L140;
    jtot++;
    g = (DD(l) - p) / (2.0f * EE(l - 1));
    r = slapy2_(g, 1.0f);
    g = DD(m - 1) - p + EE(l - 1) / (g + f_signf(r, g));
    s = 1.0f; c = 1.0f; p = 0.0f;
    for (int i = m - 1; i >= l; --i) {
      f = s * EE(i - 1);
      bb = c * EE(i - 1);
      slartg_(g, f, &c, &s, &r);
      if (i != m - 1) EE(i) = r;
      g = DD(i) - p;
      r = (DD(i - 1) - g) * s + 2.0f * c * bb;
      p = s * r;
      DD(i) = g + p;
      g = c * r - bb;
      CC(i - 1) = c; SN(i - 1) = -s;
    }
    mm = m - l + 1;
    for (int j = mm - 1; j >= 1; --j) {
      float ct = CC(l + j - 2), st = SN(l + j - 2);
      for (int i = 0; i < n; ++i) {
        float tz = ZZ(i, l + j - 1);
        ZZ(i, l + j - 1) = ct * tz - st * ZZ(i, l + j - 2);
        ZZ(i, l + j - 2) = st * tz + ct * ZZ(i, l + j - 2);
      }
    }
    DD(l - 1) -= p;
    EE(l - 1) = g;
    goto L40;
L80:
    DD(l - 1) = p;
    l++;
    if (l <= lend) goto L40;
    goto L140;
  } else {
L90:
    if (l != lend) {
      for (m = l; m >= lend + 1; --m) {
        tst = EE(m - 2) * EE(m - 2);
        if (tst <= (eps2 * fabsf(DD(m - 1))) * fabsf(DD(m - 2)) + safmin) goto L110;
      }
    }
    m = lend;
L110:
    if (m > lend) EE(m - 2) = 0.0f;
    p = DD(l - 1);
    if (m == l) goto L130;
    if (m == l - 1) {
      slaev2_(DD(l - 2), EE(l - 2), DD(l - 1), &rt1, &rt2, &c, &s);
      for (int i = 0; i < n; ++i) {
        float tz = ZZ(i, l - 1);
        ZZ(i, l - 1) = c * tz - s * ZZ(i, l - 2);
        ZZ(i, l - 2) = s * tz + c * ZZ(i, l - 2);
      }
      DD(l - 2) = rt1; DD(l - 1) = rt2; EE(l - 2) = 0.0f;
      l -= 2;
      if (l >= lend) goto L90;
      goto L140;
    }
    if (jtot == nmaxit) goto L140;
    jtot++;
    g = (DD(l - 2) - p) / (2.0f * EE(l - 2));
    r = slapy2_(g, 1.0f);
    g = DD(m - 1) - p + EE(l - 2) / (g + f_signf(r, g));
    s = 1.0f; c = 1.0f; p = 0.0f;
    for (int i = m; i <= l - 1; ++i) {
      f = s * EE(i - 1);
      bb = c * EE(i - 1);
      slartg_(g, f, &c, &s, &r);
      if (i != m) EE(i - 2) = r;
      g = DD(i - 1) - p;
      r = (DD(i) - g) * s + 2.0f * c * bb;
      p = s * r;
      DD(i - 1) = g + p;
      g = c * r - bb;
      CC(i - 1) = c; SN(i - 1) = s;
    }
    mm = l - m + 1;
    for (int j = 1; j <= mm - 1; ++j) {
      float ct = CC(m + j - 2), st = SN(m + j - 2);
      for (int i = 0; i < n; ++i) {
        float tz = ZZ(i, m + j - 1);
        ZZ(i, m + j - 1) = ct * tz - st * ZZ(i, m + j - 2);
        ZZ(i, m + j - 2) = st * tz + ct * ZZ(i, m + j - 2);
      }
    }
    DD(l - 1) -= p;
    EE(l - 2) = g;
    goto L90;
L130:
    DD(l - 1) = p;
    l--;
    if (l >= lend) goto L90;
    goto L140;
  }
L140:
  if (jtot < nmaxit) goto L10;
  goto L160;
L160:
  for (int ii = 2; ii <= n; ++ii) {
    int i = ii - 1, k = i;
    float pp = DD(i - 1);
    for (int j = ii; j <= n; ++j)
      if (DD(j - 1) < pp) { k = j; pp = DD(j - 1); }
    if (k != i) {
      DD(k - 1) = DD(i - 1); DD(i - 1) = pp;
      for (int row = 0; row < n; ++row) {
        float t2 = ZZ(row, i - 1); ZZ(row, i - 1) = ZZ(row, k - 1); ZZ(row, k - 1) = t2;
      }
    }
  }
}

// ssyevd('V','L') for 3x3: ssytd2 -> ssteqr('I') -> sormtr. Workspace in LDS (w = base+lane).
__device__ void eigh3f_lds(float A00, float A10, float A20, float A11, float A21, float A22,
                           float* w, float V[3][3]) {
  float taui, v2, beta;
  float alpha = A10;
  float xnorm = fabsf(A20);
  if (xnorm == 0.0f) {
    taui = 0.0f; beta = alpha; v2 = 0.0f;
  } else {
    beta = -f_signf(slapy2_(alpha, xnorm), alpha);
    taui = (beta - alpha) / beta;
    v2 = A20 * (1.0f / (alpha - beta));
  }
  float a11 = A11, a21 = A21, a22 = A22;
  if (taui != 0.0f) {
    float w0 = taui * (a11 + a21 * v2);
    float w1 = taui * (a21 + a22 * v2);
    float al = -0.5f * taui * (w0 + w1 * v2);
    w0 += al; w1 += al * v2;
    a11 -= 2.0f * w0;
    a21 -= (v2 * w0 + w1);
    a22 -= 2.0f * (v2 * w1);
  }
  DD(0) = A00; DD(1) = a11; DD(2) = a22;
  EE(0) = beta; EE(1) = a21;
  // Z = I
  ZZ(0, 0) = 1.0f; ZZ(0, 1) = 0.0f; ZZ(0, 2) = 0.0f;
  ZZ(1, 0) = 0.0f; ZZ(1, 1) = 1.0f; ZZ(1, 2) = 0.0f;
  ZZ(2, 0) = 0.0f; ZZ(2, 1) = 0.0f; ZZ(2, 2) = 1.0f;

  ssteqr3_lds(w);

  // sormtr: Z := H1 * Z, H1 = I - tau*u*u^T, u = [0, 1, v2]
  for (int k = 0; k < 3; ++k) {
    float t = taui * (ZZ(1, k) + v2 * ZZ(2, k));
    ZZ(1, k) -= t;
    ZZ(2, k) -= t * v2;
  }
  for (int i = 0; i < 3; ++i)
    for (int k = 0; k < 3; ++k) V[i][k] = ZZ(i, k);
}

// wave64 u32 min-reduce via DPP (row_shr 1/2/4/8 + row_bcast15/31); result valid in lane 63.
__device__ __forceinline__ unsigned wave_min_dpp(unsigned v) {
  unsigned t;
  t = (unsigned)__builtin_amdgcn_update_dpp(-1, (int)v, 0x111, 0xf, 0xf, false); v = t < v ? t : v;
  t = (unsigned)__builtin_amdgcn_update_dpp(-1, (int)v, 0x112, 0xf, 0xf, false); v = t < v ? t : v;
  t = (unsigned)__builtin_amdgcn_update_dpp(-1, (int)v, 0x114, 0xf, 0xf, false); v = t < v ? t : v;
  t = (unsigned)__builtin_amdgcn_update_dpp(-1, (int)v, 0x118, 0xf, 0xf, false); v = t < v ? t : v;
  t = (unsigned)__builtin_amdgcn_update_dpp(-1, (int)v, 0x142, 0xa, 0xf, false); v = t < v ? t : v;
  t = (unsigned)__builtin_amdgcn_update_dpp(-1, (int)v, 0x143, 0xc, 0xf, false); v = t < v ? t : v;
  return v;
}

// ---------------- Kernel A: wave-per-point KNN (FROZEN at R12 best: 72.3 us) ----------------

__global__ __launch_bounds__(1024, 8) void knn_kernel(const float* __restrict__ coords,
                                                      float* __restrict__ nbrD,
                                                      int* __restrict__ nbrI,
                                                      float* __restrict__ d16) {
  __shared__ float4 scs[NPTS];     // 64 KB: {x, y, z, sq}
  int tid = threadIdx.x;
  int wid = tid >> 6;
  int lane = tid & 63;
  int P = blockIdx.x * 16 + wid;   // 16 | 4096, no batch crossing
  int b = P >> 12;
  int p = P & (NPTS - 1);
  const float* cb = coords + (size_t)b * NPTS * 3;

  for (int i = tid; i < NPTS; i += 1024) {
    float x = cb[3 * i + 0], y = cb[3 * i + 1], z = cb[3 * i + 2];
    float sq = (x * x + y * y) + z * z;   // exact ref expression order
    scs[i] = make_float4(x, y, z, sq);
  }
  __syncthreads();

  float4 ci = scs[p];
  float xi = ci.x, yi = ci.y, zi = ci.z, sqi = ci.w;

  const double INF = __hiloint2double(0x7FF00000, 0);   // +inf sentinel (> any composite)
  double L[LTOP];
#pragma unroll
  for (int t = 0; t < LTOP; ++t) L[t] = INF;

#pragma unroll 8
  for (int k = 0; k < NPTS / 64; ++k) {
    int j = k * 64 + lane;
    float4 cj = scs[j];                       // one ds_read_b128
    float dot = (xi * cj.x + yi * cj.y) + zi * cj.z;
    float d2 = (sqi - 2.0f * dot) + cj.w;     // exact ref expression order
    unsigned kb = __float_as_uint(d2) & 0x7FFFFFFFu;   // |d2| bits
    double cur = __hiloint2double((int)kb, j);         // bit-concat composite key
    double m1 = fmax(cur, L[0]);
    double m2 = fmax(cur, L[1]);
    double m3 = fmax(cur, L[2]);
    double m4 = fmax(cur, L[3]);
    double m5 = fmax(cur, L[4]);
    double m6 = fmax(cur, L[5]);
    L[0] = fmin(L[0], cur);
    L[1] = fmin(L[1], m1);
    L[2] = fmin(L[2], m2);
    L[3] = fmin(L[3], m3);
    L[4] = fmin(L[4], m4);
    L[5] = fmin(L[5], m5);
    L[6] = fmin(L[6], m6);
  }

  unsigned resHi = 0, resLo = 0;
  for (int r = 0; r < NNB; ++r) {
    unsigned hi0 = (unsigned)__double2hiint(L[0]);
    unsigned lo0 = (unsigned)__double2loint(L[0]);
    unsigned gh = wave_min_dpp(hi0);
    gh = (unsigned)__builtin_amdgcn_readlane((int)gh, 63);
    unsigned lom = (hi0 == gh) ? lo0 : 0xFFFFFFFFu;
    unsigned gl = wave_min_dpp(lom);
    gl = (unsigned)__builtin_amdgcn_readlane((int)gl, 63);
    bool mine = (hi0 == gh) && (lo0 == gl);   // idx embedded -> unique owner
#pragma unroll
    for (int t = 0; t < LTOP - 1; ++t) L[t] = mine ? L[t + 1] : L[t];
    L[LTOP - 1] = mine ? INF : L[LTOP - 1];
    if (lane == r) { resHi = gh; resLo = gl; }
  }

  if (lane < NNB) {
    float dist = sqrtf(__uint_as_float(resHi));   // hi word IS the f32 |d2| key bits
    nbrD[(size_t)lane * NTOT + P] = dist;         // transposed [NNB][NTOT]
    nbrI[(size_t)lane * NTOT + P] = (int)resLo;   // lo word IS the index
    if (lane == 16) d16[P] = dist;                // dsort[:,16]
  }
}

// ---------------- Kernel C: fused radius + SHOT LRF + log-map + histogram ----------------
// Radius: bit-identical LDS-staged sequential f32 chain per block (all blocks agree).
// Gathers issued before the chain (latency hides under it). Eigh workspace in LDS
// (lane-major, stride 64): runtime-indexed LAPACK arrays would otherwise spill to
// scratch -> ~hundreds of cycles/access at 0.25 waves/SIMD (R13: VALUBusy 6.8%).

__global__ __launch_bounds__(64) void shot_kernel(const float* __restrict__ coords,
                                                  const float* __restrict__ d16,
                                                  const float* __restrict__ nbrD,
                                                  const int* __restrict__ nbrI,
                                                  float* __restrict__ out) {
  __shared__ float buf[NPTS];        // 16 KB: d16 of this block's batch
  __shared__ float ews[18 * 64];     // 4.5 KB: per-lane eigh workspace, stride 64
  int lane = threadIdx.x;
  int g = blockIdx.x * 64 + lane;    // grid exact: 256 blocks x 64
  int b = g >> 12;
  int p = g & (NPTS - 1);
  const float* cb = coords + (size_t)b * NPTS * 3;

  // stage d16 (coalesced)
  for (int i = lane; i < NPTS; i += 64) buf[i] = d16[(size_t)b * NPTS + i];

  // issue all gathers before the radius chain (latency hides under it)
  int jj[NNB];
  float dd[NNB];
#pragma unroll
  for (int k = 0; k < NNB; ++k) {
    jj[k] = nbrI[(size_t)k * NTOT + g];   // coalesced
    dd[k] = nbrD[(size_t)k * NTOT + g];   // coalesced
  }
  float gx[NNB], gy[NNB], gz[NNB];
#pragma unroll
  for (int k = 0; k < NNB; ++k) {
    int j = jj[k];
    gx[k] = cb[j * 3 + 0];                // scattered gathers, in flight during chain
    gy[k] = cb[j * 3 + 1];
    gz[k] = cb[j * 3 + 2];
  }
  float xi = cb[p * 3 + 0], yi = cb[p * 3 + 1], zi = cb[p * 3 + 2];

  __syncthreads();
  // bit-identical sequential f32 radius chain
  float s = 0.0f;
  for (int k = 0; k < NPTS; ++k) s += buf[k];   // same-addr LDS broadcast reads
  float radius = s / 4096.0f;

  float fill = 2.0f * radius / sqrtf(3.0f);

  float nbx[NNB], nby[NNB], nbz[NNB], dk[NNB];
#pragma unroll
  for (int k = 0; k < NNB; ++k) {
    float nx, ny, nz;
    if (dd[k] > radius) { nx = fill; ny = fill; nz = fill; }
    else {
      nx = gx[k] - xi;
      ny = gy[k] - yi;
      nz = gz[k] - zi;
    }
    nbx[k] = nx; nby[k] = ny; nbz[k] = nz;
    dk[k] = sqrtf((nx * nx + ny * ny) + nz * nz);
  }

  float wsum = 0.0f;
  float c00 = 0, c11 = 0, c22 = 0;
  float c01 = 0, c10 = 0, c02 = 0, c20 = 0, c12 = 0, c21 = 0;
  for (int k = 0; k < NNB; ++k) {
    float w = fmaxf(radius - dk[k], 0.0f);
    wsum += w;
    float wx = w * nbx[k], wy = w * nby[k], wz = w * nbz[k];
    c00 += wx * nbx[k]; c01 += wx * nby[k]; c02 += wx * nbz[k];
    c10 += wy * nbx[k]; c11 += wy * nby[k]; c12 += wy * nbz[k];
    c20 += wz * nbx[k]; c21 += wz * nby[k]; c22 += wz * nbz[k];
  }
  float den = wsum + 1e-12f;
  float a00 = c00 / den, a11 = c11 / den, a22 = c22 / den;
  float a01 = c01 / den, a10 = c10 / den;
  float a02 = c02 / den, a20 = c20 / den;
  float a12 = c12 / den, a21 = c21 / den;
  float A10 = 0.5f * (a01 + a10);
  float A20 = 0.5f * (a02 + a20);
  float A21 = 0.5f * (a12 + a21);

  float V[3][3];
  eigh3f_lds(a00, A10, A20, a11, A21, a22, &ews[lane], V);

  float xax0 = V[0][2], xax1 = V[1][2], xax2 = V[2][2];
  float zax0 = V[0][0], zax1 = V[1][0], zax2 = V[2][0];

  {
    int pos = 0, neg = 0;
    for (int k = 0; k < NNB; ++k) {
      float dt = (nbx[k] * xax0 + nby[k] * xax1) + nbz[k] * xax2;
      if (dt >= 0.0f) pos++; else neg++;
    }
    if (pos < neg) { xax0 = -xax0; xax1 = -xax1; xax2 = -xax2; }
  }
  {
    int pos = 0, neg = 0;
    for (int k = 0; k < NNB; ++k) {
      float dt = (nbx[k] * zax0 + nby[k] * zax1) + nbz[k] * zax2;
      if (dt >= 0.0f) pos++; else neg++;
    }
    if (pos < neg) { zax0 = -zax0; zax1 = -zax1; zax2 = -zax2; }
  }
  float yax0 = zax1 * xax2 - zax2 * xax1;
  float yax1 = zax2 * xax0 - zax0 * xax2;
  float yax2 = zax0 * xax1 - zax1 * xax0;

  float hist[NBINS * NBINS];
  for (int k = 0; k < NBINS * NBINS; ++k) hist[k] = 0.0f;
  float stp = 2.0f * radius / (float)NBINS;
  for (int k = 0; k < NNB; ++k) {
    float u = (nbx[k] * xax0 + nby[k] * xax1) + nbz[k] * xax2;
    float v = (nbx[k] * yax0 + nby[k] * yax1) + nbz[k] * yax2;
    float pn = sqrtf(u * u + v * v);
    float sc = dk[k] / (pn + 1e-12f);
    float pu = u * sc, pv = v * sc;
    float bxf = floorf((pu + radius) / stp);
    float byf = floorf((pv + radius) / stp);
    if (bxf >= 0.0f && bxf < (float)NBINS && byf >= 0.0f && byf < (float)NBINS) {
      int bx = (int)bxf, by = (int)byf;
      hist[by * NBINS + bx] += 1.0f;
    }
  }
  float cvals[NBINS];
  for (int i = 0; i < NBINS; ++i) cvals[i] = ((float)i * stp - radius) + 0.5f * stp;
  float nrm2 = 0.0f;
  for (int i = 0; i < NBINS; ++i) {
    for (int j = 0; j < NBINS; ++j) {
      float wgt = radius - sqrtf(cvals[i] * cvals[i] + cvals[j] * cvals[j]);
      float h = hist[i * NBINS + j] * wgt;
      hist[i * NBINS + j] = h;
      nrm2 += h * h;
    }
  }
  float nrm = sqrtf(nrm2);
  for (int k = 0; k < NBINS * NBINS; ++k) {
    out[(size_t)g * (NBINS * NBINS) + k] = hist[k] / nrm;
  }
}

// ---------------- Launch ----------------

extern "C" void kernel_launch(void* const* d_in, const int* in_sizes, int n_in,
                              void* d_out, int out_size, void* d_ws, size_t ws_size,
                              hipStream_t stream) {
  const float* coords = (const float*)d_in[0];
  float* out = (float*)d_out;

  float* wsf = (float*)d_ws;
  float* d16 = wsf + 8;                           // 16384 floats
  float* nbrD = wsf + 8 + (size_t)NTOT;           // [NNB][NTOT] floats
  int* nbrI = (int*)(nbrD + (size_t)NNB * NTOT);  // [NNB][NTOT] ints

  knn_kernel<<<NTOT / 16, 1024, 0, stream>>>(coords, nbrD, nbrI, d16);
  shot_kernel<<<NTOT / 64, 64, 0, stream>>>(coords, d16, nbrD, nbrI, out);
}